// Round 12
// baseline (2733.546 us; speedup 1.0000x reference)
//
#include <hip/hip_runtime.h>
#include <hip/hip_bf16.h>
#include <math.h>

#define B_BATCH 64
#define T_STEPS 256
#define C_COMP  64

// ws layout: floats [0..191] avec, [192..383] cvec; byte 2048+ : scan bf16 weights
#define WSW_BYTE_OFF 2048
#define WHH_OFF 0
#define Q1_OFF 12288
#define K1_OFF 20480
#define Q2_OFF 28672
#define K2_OFF 45056
#define Q3_OFF 61440
#define K3_OFF 77824
// classifier scratch (bytes)
#define C1WB_BYTE 262144
#define C2WB_BYTE 17039360
#define H1B_BYTE  21233664
#define H2B_BYTE  88342528
#define MB16_BYTE 121896960ULL

// output offsets (floats)
#define MAT_OFF  128
#define TL_OFF   67108992
#define PRED_OFF 67141760
#define XC_OFF   68186240

// LDS strides
#define GST 196   // gates f32
#define HS  68    // h32 f32
#define TS  68    // tf f32
#define GBS 68    // gbias f32

typedef __attribute__((ext_vector_type(8))) short short8;
typedef __attribute__((ext_vector_type(4))) float f32x4;
#define MFMA16(a,b,c) __builtin_amdgcn_mfma_f32_16x16x32_bf16(a,b,c,0,0,0)

__device__ __forceinline__ float fsigm(float v) {
    return __builtin_amdgcn_rcpf(1.0f + __expf(-v));
}
__device__ __forceinline__ float ftanh(float v) {
    return 1.0f - 2.0f * __builtin_amdgcn_rcpf(__expf(2.0f * v) + 1.0f);
}
__device__ __forceinline__ short f2bs(float f) {  // RNE f32->bf16 bits
    unsigned u = __float_as_uint(f);
    u += 0x7fffu + ((u >> 16) & 1u);
    return (short)(u >> 16);
}
__device__ __forceinline__ float bf2f(short s) {
    return __uint_as_float(((unsigned)(unsigned short)s) << 16);
}
// packed bf16x2 via known-good bit-manip RNE (lo16 = a, hi16 = b)
__device__ __forceinline__ unsigned pk2(float a, float b) {
    return (unsigned)(unsigned short)f2bs(a) | ((unsigned)(unsigned short)f2bs(b) << 16);
}
// LDS-only barrier (no vmcnt drain; in-loop global stores have no in-kernel consumer)
__device__ __forceinline__ void bar_lds() {
    asm volatile("s_waitcnt lgkmcnt(0)" ::: "memory");
    __builtin_amdgcn_s_barrier();
}
__device__ __forceinline__ int xorr(int row) { return ((row >> 1) & 7) << 3; }

__device__ __forceinline__ void async16(void* lds, const void* g) {
    __builtin_amdgcn_global_load_lds((const __attribute__((address_space(1))) void*)g,
                                     (__attribute__((address_space(3))) void*)lds, 16, 0, 0);
}

// ---------------- precompute rank-1 embedding+input path --------------------------------
__global__ void precompute_kernel(const float* __restrict__ w_ih,
                                  const float* __restrict__ embed_w,
                                  const float* __restrict__ embed_b,
                                  const float* __restrict__ b_ih,
                                  float* __restrict__ avec, float* __restrict__ cvec)
{
    int g = threadIdx.x;
    if (g < 192) {
        float a = 0.f, c = 0.f;
        for (int e = 0; e < 32; ++e) {
            float w = w_ih[g * 32 + e];
            a += w * embed_w[e];
            c += w * embed_b[e];
        }
        avec[g] = a;
        cvec[g] = c + b_ih[g];
    }
}

// all fp32->bf16 weight conversions in ONE launch; 1024 elems per block (256 thr x 4)
__global__ __launch_bounds__(256) void tobf16_all_kernel(
    const float* __restrict__ s_whh,
    const float* __restrict__ s_q1, const float* __restrict__ s_k1,
    const float* __restrict__ s_q2, const float* __restrict__ s_k2,
    const float* __restrict__ s_q3, const float* __restrict__ s_k3,
    const float* __restrict__ s_c1, const float* __restrict__ s_c2,
    short* __restrict__ wsw, short* __restrict__ c1wb, short* __restrict__ c2wb)
{
    int bb = blockIdx.x;
    const float* src; short* dst; int n;
    if      (bb < 12)   { src = s_whh; dst = wsw + WHH_OFF; n = 12288;            }
    else if (bb < 20)   { src = s_q1;  dst = wsw + Q1_OFF;  n = 8192;  bb -= 12;  }
    else if (bb < 28)   { src = s_k1;  dst = wsw + K1_OFF;  n = 8192;  bb -= 20;  }
    else if (bb < 44)   { src = s_q2;  dst = wsw + Q2_OFF;  n = 16384; bb -= 28;  }
    else if (bb < 60)   { src = s_k2;  dst = wsw + K2_OFF;  n = 16384; bb -= 44;  }
    else if (bb < 76)   { src = s_q3;  dst = wsw + Q3_OFF;  n = 16384; bb -= 60;  }
    else if (bb < 92)   { src = s_k3;  dst = wsw + K3_OFF;  n = 16384; bb -= 76;  }
    else if (bb < 8284) { src = s_c1;  dst = c1wb;          n = 8388608; bb -= 92; }
    else                { src = s_c2;  dst = c2wb;          n = 2097152; bb -= 8284; }
    const int i = bb * 1024 + threadIdx.x * 4;
    if (i < n) {
        float4 v = *reinterpret_cast<const float4*>(&src[i]);
        uint2 p;
        p.x = pk2(v.x, v.y);
        p.y = pk2(v.z, v.w);
        *reinterpret_cast<uint2*>(&dst[i]) = p;
    }
}

// swapped-operand MLP layer: wave computes strips s0,s1 x all 4 row-groups.
// mfma(W_frag, act_frag): lane holds act-row (g*16+ln), 4 consecutive out-cols -> packed b64 stores.
template<int KST, int AST, bool RELU>
__device__ __forceinline__ void two_strip_sw(
    const short* __restrict__ A,
    const short8* __restrict__ B0, const short8* __restrict__ B1,
    const f32x4 bias0, const f32x4 bias1,
    short* __restrict__ outb, const int s0, const int s1, const int ln, const int lh)
{
    f32x4 acc0[4], acc1[4];
#pragma unroll
    for (int g = 0; g < 4; ++g) { acc0[g] = bias0; acc1[g] = bias1; }
#pragma unroll
    for (int kk = 0; kk < KST; ++kk)
#pragma unroll
        for (int g = 0; g < 4; ++g) {
            const int row = g * 16 + ln;
            short8 a = *(const short8*)&A[row * AST + ((kk * 32 + lh * 8) ^ xorr(row))];
            acc0[g] = MFMA16(B0[kk], a, acc0[g]);
            acc1[g] = MFMA16(B1[kk], a, acc1[g]);
        }
#pragma unroll
    for (int g = 0; g < 4; ++g) {
        const int row = g * 16 + ln;
        f32x4 v0 = acc0[g], v1 = acc1[g];
        if (RELU) {
#pragma unroll
            for (int q = 0; q < 4; ++q) { v0[q] = fmaxf(v0[q], 0.f); v1[q] = fmaxf(v1[q], 0.f); }
        }
        uint2 p0, p1;
        p0.x = pk2(v0[0], v0[1]); p0.y = pk2(v0[2], v0[3]);
        p1.x = pk2(v1[0], v1[1]); p1.y = pk2(v1[2], v1[3]);
        *(uint2*)&outb[row * 128 + ((s0 * 16 + lh * 4) ^ xorr(row))] = p0;
        *(uint2*)&outb[row * 128 + ((s1 * 16 + lh * 4) ^ xorr(row))] = p1;
    }
}

// ---------------- the scan: one block (8 waves) per batch, 8 short phases ----------------
__global__ __launch_bounds__(512) void scan_kernel(
    const float* __restrict__ x, const float* __restrict__ b_hh,
    const float* __restrict__ avec, const float* __restrict__ cvec,
    const short* __restrict__ wsw,
    const float* __restrict__ q1b, const float* __restrict__ q2b, const float* __restrict__ q3b,
    const float* __restrict__ k1b, const float* __restrict__ k2b, const float* __restrict__ k3b,
    const float* __restrict__ gate_bias,
    const float* __restrict__ pred_w, const float* __restrict__ pred_b,
    float* __restrict__ matrices, float* __restrict__ predicted,
    float* __restrict__ xcopy,
    short* __restrict__ mb16, const int use_mb16)
{
    __shared__ __align__(16) short hb  [64 * 64];   // post-BTP h (F2 -> P1)
    __shared__ __align__(16) short hbN [64 * 64];   // post-GRU h (P2 -> L1)
    __shared__ __align__(16) short hbT [64 * 64];   // post-GRU h^T (P2 -> F2)
    __shared__ __align__(16) float h32 [64 * HS];   // fp32 post-BTP h (F2 -> P2 hold / predictor)
    __shared__ __align__(16) short qf  [64 * 128];
    __shared__ __align__(16) short kf  [64 * 128];
    __shared__ __align__(16) float gbias_s[64 * GBS];
    __shared__ __align__(16) char arena[65536];
    // small arrays: explicitly 16B-aligned — f32x4 reads below require it
    __shared__ __align__(16) float avec_s[192];
    __shared__ __align__(16) float cvec_s[192];
    __shared__ __align__(16) float bhh_s[192];
    __shared__ __align__(16) float pw_s[64];
    __shared__ __align__(16) float xrow[64];
    __shared__ __align__(16) float red[8];

    float* gates = (float*)arena;                   // [64][196] f32  P1->P2
    short* act2q = (short*)arena;                   // [64][128] swz  L2->L3
    short* act2k = (short*)(arena + 16384);
    short* act1q = (short*)(arena + 32768);         // L1->L2
    short* act1k = (short*)(arena + 49152);
    float* tf    = (float*)arena;                   // [64][68] f32   E->F1
    short* tb    = (short*)(arena + 20480);         // [64][64] swz   F1->F2

    const int tid = threadIdx.x;
    const int b = blockIdx.x;
    const int w = tid >> 6, lane = tid & 63;
    const int ln = lane & 15, lh = lane >> 4;
    const int path = w >> 2;                        // MLP: 0 = q, 1 = k
    const int wq = w & 3;

    for (int i = tid; i < 64 * 64; i += 512) { hb[i] = 0; hbN[i] = 0; hbT[i] = 0; }
    for (int i = tid; i < 64 * HS; i += 512) h32[i] = 0.f;
    for (int i = tid; i < 4096; i += 512)
        gbias_s[(i >> 6) * GBS + (i & 63)] = gate_bias[i];
    if (tid < 192) { avec_s[tid] = avec[tid]; cvec_s[tid] = cvec[tid]; bhh_s[tid] = b_hh[tid]; }
    if (tid < 64) { pw_s[tid] = pred_w[tid]; xrow[tid] = x[(size_t)b * T_STEPS * 64 + tid]; }
    const float pbv = pred_b[0];

    // ---- weight fragments (A-operand = weight rows = output cols), constant across t ----
    const short* whh_b = wsw + WHH_OFF;
    const short* l1w = path ? wsw + K1_OFF : wsw + Q1_OFF;
    const short* l2w = path ? wsw + K2_OFF : wsw + Q2_OFF;
    const short* l3w = path ? wsw + K3_OFF : wsw + Q3_OFF;
    const float* l1b = path ? k1b : q1b;
    const float* l2b = path ? k2b : q2b;
    const float* l3b = path ? k3b : q3b;

    short8 Bg[2][2], B1[2][2], B2[2][4], B3[2][4];
#pragma unroll
    for (int kk = 0; kk < 2; ++kk)
        Bg[0][kk] = *(const short8*)&whh_b[(w * 16 + ln) * 64 + kk * 32 + lh * 8];
    if (w < 4) {
#pragma unroll
        for (int kk = 0; kk < 2; ++kk)
            Bg[1][kk] = *(const short8*)&whh_b[((w + 8) * 16 + ln) * 64 + kk * 32 + lh * 8];
    }
#pragma unroll
    for (int s = 0; s < 2; ++s) {
        const int strip = wq + s * 4;
#pragma unroll
        for (int kk = 0; kk < 2; ++kk)
            B1[s][kk] = *(const short8*)&l1w[(strip * 16 + ln) * 64 + kk * 32 + lh * 8];
#pragma unroll
        for (int kk = 0; kk < 4; ++kk) {
            B2[s][kk] = *(const short8*)&l2w[(strip * 16 + ln) * 128 + kk * 32 + lh * 8];
            B3[s][kk] = *(const short8*)&l3w[(strip * 16 + ln) * 128 + kk * 32 + lh * 8];
        }
    }
    // per-lane bias vectors (4 consecutive out-cols each); global, 16B-aligned offsets
    const f32x4 b1v0 = *(const f32x4*)&l1b[wq * 16 + lh * 4];
    const f32x4 b1v1 = *(const f32x4*)&l1b[(wq + 4) * 16 + lh * 4];
    const f32x4 b2v0 = *(const f32x4*)&l2b[wq * 16 + lh * 4];
    const f32x4 b2v1 = *(const f32x4*)&l2b[(wq + 4) * 16 + lh * 4];
    const f32x4 b3v0 = *(const f32x4*)&l3b[wq * 16 + lh * 4];
    const f32x4 b3v1 = *(const f32x4*)&l3b[(wq + 4) * 16 + lh * 4];
    __syncthreads();

    for (int t = 0; t < T_STEPS; ++t) {
        // ===== P1: x prefetch (+xcopy store), predictor(t-1), gates = h @ w_hh^T =====
        float xnext = 0.f;
        if (tid < 64 && t + 1 < T_STEPS) {
            xnext = x[((size_t)b * T_STEPS + t + 1) * 64 + tid];
            // output 5 = x[:,1:,:] — written from the already-loaded prefetch register
            xcopy[((size_t)b * (T_STEPS - 1) + t) * 64 + tid] = xnext;
        }
        if (t > 0) {
            const int c = tid >> 3, j0 = (tid & 7) * 8;
            f32x4 h0 = *(const f32x4*)&h32[c * HS + j0];
            f32x4 h1 = *(const f32x4*)&h32[c * HS + j0 + 4];
            f32x4 w0 = *(const f32x4*)&pw_s[j0];
            f32x4 w1 = *(const f32x4*)&pw_s[j0 + 4];
            float p = 0.f;
#pragma unroll
            for (int q = 0; q < 4; ++q) p = fmaf(h0[q], w0[q], fmaf(h1[q], w1[q], p));
            p += __shfl_xor(p, 1); p += __shfl_xor(p, 2); p += __shfl_xor(p, 4);
            if ((lane & 7) == 0)
                predicted[((size_t)b * (T_STEPS - 1) + (t - 1)) * 64 + c] = p + pbv;
        }
        {
            f32x4 accA[4], accB[4];
            const f32x4 bhA = *(const f32x4*)&bhh_s[w * 16 + lh * 4];
#pragma unroll
            for (int g = 0; g < 4; ++g) accA[g] = bhA;
            if (w < 4) {
                const f32x4 bhB = *(const f32x4*)&bhh_s[(w + 8) * 16 + lh * 4];
#pragma unroll
                for (int g = 0; g < 4; ++g) accB[g] = bhB;
            }
#pragma unroll
            for (int kk = 0; kk < 2; ++kk)
#pragma unroll
                for (int g = 0; g < 4; ++g) {
                    const int row = g * 16 + ln;
                    short8 hv = *(const short8*)&hb[row * 64 + ((kk * 32 + lh * 8) ^ xorr(row))];
                    accA[g] = MFMA16(Bg[0][kk], hv, accA[g]);
                    if (w < 4) accB[g] = MFMA16(Bg[1][kk], hv, accB[g]);
                }
#pragma unroll
            for (int g = 0; g < 4; ++g)
                *(f32x4*)&gates[(g * 16 + ln) * GST + w * 16 + lh * 4] = accA[g];
            if (w < 4) {
#pragma unroll
                for (int g = 0; g < 4; ++g)
                    *(f32x4*)&gates[(g * 16 + ln) * GST + (w + 8) * 16 + lh * 4] = accB[g];
            }
        }
        bar_lds();

        // ===== P2: GRU elementwise (vectorized LDS) -> h32, hbN, hbT =====
        {
            const int c = tid >> 3, j0 = (tid & 7) * 8;
            const float xv = xrow[c];
            unsigned pk[4];
#pragma unroll
            for (int h2 = 0; h2 < 2; ++h2) {
                const int jh = j0 + h2 * 4;
                f32x4 gr4 = *(const f32x4*)&gates[c * GST + jh];
                f32x4 gz4 = *(const f32x4*)&gates[c * GST + 64 + jh];
                f32x4 gn4 = *(const f32x4*)&gates[c * GST + 128 + jh];
                f32x4 ho4 = *(const f32x4*)&h32[c * HS + jh];
                f32x4 ar4 = *(const f32x4*)&avec_s[jh];
                f32x4 az4 = *(const f32x4*)&avec_s[64 + jh];
                f32x4 an4 = *(const f32x4*)&avec_s[128 + jh];
                f32x4 cr4 = *(const f32x4*)&cvec_s[jh];
                f32x4 cz4 = *(const f32x4*)&cvec_s[64 + jh];
                f32x4 cn4 = *(const f32x4*)&cvec_s[128 + jh];
                f32x4 hn4;
#pragma unroll
                for (int q = 0; q < 4; ++q) {
                    const float r = fsigm(gr4[q] + fmaf(xv, ar4[q], cr4[q]));
                    const float z = fsigm(gz4[q] + fmaf(xv, az4[q], cz4[q]));
                    const float n = ftanh(fmaf(r, gn4[q], fmaf(xv, an4[q], cn4[q])));
                    hn4[q] = fmaf(z, ho4[q] - n, n);
                }
                *(f32x4*)&h32[c * HS + jh] = hn4;
                const unsigned plo = pk2(hn4[0], hn4[1]);
                const unsigned phi = pk2(hn4[2], hn4[3]);
                pk[h2 * 2] = plo; pk[h2 * 2 + 1] = phi;
                // transposed scalar stores (bf16 halves of the packed words)
                hbT[(jh + 0) * 64 + (c ^ xorr(jh + 0))] = (short)plo;
                hbT[(jh + 1) * 64 + (c ^ xorr(jh + 1))] = (short)(plo >> 16);
                hbT[(jh + 2) * 64 + (c ^ xorr(jh + 2))] = (short)phi;
                hbT[(jh + 3) * 64 + (c ^ xorr(jh + 3))] = (short)(phi >> 16);
            }
            uint4 pv; pv.x = pk[0]; pv.y = pk[1]; pv.z = pk[2]; pv.w = pk[3];
            *(uint4*)&hbN[c * 64 + (j0 ^ xorr(c))] = pv;
        }
        bar_lds();

        // ===== L1-L3: q / k MLPs (swapped, packed stores) =====
        two_strip_sw<2, 64,  true >(hbN, B1[0], B1[1], b1v0, b1v1,
                                    path ? act1k : act1q, wq, wq + 4, ln, lh);
        bar_lds();
        two_strip_sw<4, 128, true >(path ? act1k : act1q, B2[0], B2[1], b2v0, b2v1,
                                    path ? act2k : act2q, wq, wq + 4, ln, lh);
        bar_lds();
        two_strip_sw<4, 128, false>(path ? act2k : act2q, B3[0], B3[1], b3v0, b3v1,
                                    path ? kf : qf, wq, wq + 4, ln, lh);
        bar_lds();

        // ===== E: tf = Q @ K^T via mfma(K_frag, Q_frag) -> packed f32x4 stores =====
        {
            const int qg = w & 3, kg = (w >> 2) * 2;
            f32x4 ac0 = {0,0,0,0}, ac1 = {0,0,0,0};
#pragma unroll
            for (int kk = 0; kk < 4; ++kk) {
                const int rq = qg * 16 + ln, rk0 = kg * 16 + ln, rk1 = (kg + 1) * 16 + ln;
                short8 bq = *(const short8*)&qf[rq * 128 + ((kk * 32 + lh * 8) ^ xorr(rq))];
                short8 a0 = *(const short8*)&kf[rk0 * 128 + ((kk * 32 + lh * 8) ^ xorr(rk0))];
                short8 a1 = *(const short8*)&kf[rk1 * 128 + ((kk * 32 + lh * 8) ^ xorr(rk1))];
                ac0 = MFMA16(a0, bq, ac0);
                ac1 = MFMA16(a1, bq, ac1);
            }
            const int qrow = qg * 16 + ln;
            *(f32x4*)&tf[qrow * TS + kg * 16 + lh * 4]       = ac0;
            *(f32x4*)&tf[qrow * TS + (kg + 1) * 16 + lh * 4] = ac1;
            float ss = 0.f;
#pragma unroll
            for (int q = 0; q < 4; ++q)
                ss = fmaf(ac0[q], ac0[q], fmaf(ac1[q], ac1[q], ss));
#pragma unroll
            for (int off = 1; off < 64; off <<= 1) ss += __shfl_xor(ss, off);
            if (lane == 0) red[w] = ss;
            if (tid < 64 && t + 1 < T_STEPS) xrow[tid] = xnext;
        }
        bar_lds();

        // ===== F1: normalize + gate -> fp32 matrices + (opt) mb16 + tb =====
        {
            const int ci = tid >> 3, j0 = (tid & 7) * 8;
            const float ssum = red[0]+red[1]+red[2]+red[3]+red[4]+red[5]+red[6]+red[7];
            const float inv = __builtin_amdgcn_rsqf(ssum);
            const size_t mbase = ((size_t)b * T_STEPS + t) * 4096;
            unsigned pk[4];
#pragma unroll
            for (int h2 = 0; h2 < 2; ++h2) {
                const int jh = j0 + h2 * 4;
                f32x4 t4  = *(const f32x4*)&tf[ci * TS + jh];
                f32x4 gb4 = *(const f32x4*)&gbias_s[ci * GBS + jh];
                f32x4 v4;
#pragma unroll
                for (int q = 0; q < 4; ++q) {
                    const float tv = t4[q] * inv;
                    const float g = fsigm(fabsf(tv) + gb4[q]);
                    v4[q] = tv * g;
                }
                pk[h2 * 2]     = pk2(v4[0], v4[1]);
                pk[h2 * 2 + 1] = pk2(v4[2], v4[3]);
                // fp32 output written directly
                *(f32x4*)&matrices[mbase + ci * 64 + jh] = v4;
            }
            uint4 pv; pv.x = pk[0]; pv.y = pk[1]; pv.z = pk[2]; pv.w = pk[3];
            if (use_mb16)
                *(uint4*)&mb16[mbase + ci * 64 + j0] = pv;
            *(uint4*)&tb[ci * 64 + (j0 ^ xorr(ci))] = pv;
        }
        bar_lds();

        // ===== F2: h_new = T @ h_post via mfma(hbT_frag, tb_frag) -> h32, hb (packed) =====
        {
            const int jg = w & 3, ig = (w >> 2) * 2;
            f32x4 hc0 = {0,0,0,0}, hc1 = {0,0,0,0};
#pragma unroll
            for (int kk = 0; kk < 2; ++kk) {
                const int rj = jg * 16 + ln, ri0 = ig * 16 + ln, ri1 = (ig + 1) * 16 + ln;
                short8 bt = *(const short8*)&tb [rj * 64 + ((kk * 32 + lh * 8) ^ xorr(rj))];
                short8 a0 = *(const short8*)&hbT[ri0 * 64 + ((kk * 32 + lh * 8) ^ xorr(ri0))];
                short8 a1 = *(const short8*)&hbT[ri1 * 64 + ((kk * 32 + lh * 8) ^ xorr(ri1))];
                hc0 = MFMA16(a0, bt, hc0);
                hc1 = MFMA16(a1, bt, hc1);
            }
            const int row = jg * 16 + ln;
            *(f32x4*)&h32[row * HS + ig * 16 + lh * 4]       = hc0;
            *(f32x4*)&h32[row * HS + (ig + 1) * 16 + lh * 4] = hc1;
            uint2 p0, p1;
            p0.x = pk2(hc0[0], hc0[1]); p0.y = pk2(hc0[2], hc0[3]);
            p1.x = pk2(hc1[0], hc1[1]); p1.y = pk2(hc1[2], hc1[3]);
            *(uint2*)&hb[row * 64 + ((ig * 16 + lh * 4) ^ xorr(row))]       = p0;
            *(uint2*)&hb[row * 64 + (((ig + 1) * 16 + lh * 4) ^ xorr(row))] = p1;
        }
        bar_lds();
    }
}

// ---------------- clf1 fallback: A fp32 (reg-convert) x B bf16 -> bf16 C ------------------
__global__ __launch_bounds__(256) void gemm1_kernel(
    const float* __restrict__ A, const short* __restrict__ Bw,
    const float* __restrict__ bias, short* __restrict__ Cb,
    const int M, const int N, const int K)
{
    __shared__ __align__(16) short Asb[128 * 64];
    __shared__ __align__(16) short Bsb[128 * 64];
    const int tid = threadIdx.x;
    const int w = tid >> 6, lane = tid & 63;
    const int ln = lane & 15, lh = lane >> 4;
    const int wr = w >> 1, wc = w & 1;

    const int ntc = N >> 7;
    const int g = blockIdx.x;
    const int xcd = g & 7, chunk = g >> 3;
    const int mt = xcd * ((M >> 7) >> 3) + chunk / ntc;
    const int nt = chunk % ntc;
    const int m0 = mt << 7, n0 = nt << 7;

    const int ar = tid >> 1;
    const int ac = (tid & 1) << 5;
    const short* bsrc = Bw + (size_t)(n0 + w * 32 + (lane >> 3)) * K + ((lane & 7) << 3);
    short* bdst = &Bsb[w * 32 * 64 + lane * 8];

    f32x4 acc[4][4];
#pragma unroll
    for (int m = 0; m < 4; ++m)
#pragma unroll
        for (int n = 0; n < 4; ++n) acc[m][n] = (f32x4){0, 0, 0, 0};

    for (int k0 = 0; k0 < K; k0 += 64) {
        const float* arow = A + (size_t)(m0 + ar) * K + k0 + ac;
        float4 av[8];
#pragma unroll
        for (int i = 0; i < 8; ++i) av[i] = *reinterpret_cast<const float4*>(arow + i * 4);
        short8 cv[4];
#pragma unroll
        for (int i = 0; i < 4; ++i) {
            cv[i][0] = f2bs(av[2*i].x);   cv[i][1] = f2bs(av[2*i].y);
            cv[i][2] = f2bs(av[2*i].z);   cv[i][3] = f2bs(av[2*i].w);
            cv[i][4] = f2bs(av[2*i+1].x); cv[i][5] = f2bs(av[2*i+1].y);
            cv[i][6] = f2bs(av[2*i+1].z); cv[i][7] = f2bs(av[2*i+1].w);
        }
        __syncthreads();
#pragma unroll
        for (int i = 0; i < 4; ++i)
            *reinterpret_cast<short8*>(&Asb[ar * 64 + ac + i * 8]) = cv[i];
#pragma unroll
        for (int i = 0; i < 4; ++i)
            async16(bdst + i * 512, bsrc + (size_t)i * 8 * K + k0);
        __syncthreads();
#pragma unroll
        for (int kk = 0; kk < 2; ++kk) {
            short8 af[4], bfr[4];
#pragma unroll
            for (int m = 0; m < 4; ++m)
                af[m] = *reinterpret_cast<const short8*>(&Asb[(wr*64 + m*16 + ln)*64 + kk*32 + lh*8]);
#pragma unroll
            for (int n = 0; n < 4; ++n)
                bfr[n] = *reinterpret_cast<const short8*>(&Bsb[(wc*64 + n*16 + ln)*64 + kk*32 + lh*8]);
#pragma unroll
            for (int m = 0; m < 4; ++m)
#pragma unroll
                for (int n = 0; n < 4; ++n)
                    acc[m][n] = MFMA16(af[m], bfr[n], acc[m][n]);
        }
    }
#pragma unroll
    for (int n = 0; n < 4; ++n) {
        const int col = n0 + wc * 64 + n * 16 + ln;
        const float bv = bias[col];
#pragma unroll
        for (int m = 0; m < 4; ++m)
#pragma unroll
            for (int q = 0; q < 4; ++q) {
                const int row = m0 + wr * 64 + m * 16 + lh * 4 + q;
                Cb[(size_t)row * N + col] = f2bs(fmaxf(acc[m][n][q] + bv, 0.f));
            }
    }
}

// ---------------- bf16 x bf16 GEMM via gload_lds (clf1 / clf2) ----------------------------
__global__ __launch_bounds__(256) void gemm2_kernel(
    const short* __restrict__ Ab, const short* __restrict__ Bw,
    const float* __restrict__ bias, short* __restrict__ Cb,
    const int M, const int N, const int K)
{
    __shared__ __align__(16) short Asb[128 * 64];
    __shared__ __align__(16) short Bsb[128 * 64];
    const int tid = threadIdx.x;
    const int w = tid >> 6, lane = tid & 63;
    const int ln = lane & 15, lh = lane >> 4;
    const int wr = w >> 1, wc = w & 1;

    const int ntc = N >> 7;
    const int g = blockIdx.x;
    const int xcd = g & 7, chunk = g >> 3;
    const int mt = xcd * ((M >> 7) >> 3) + chunk / ntc;
    const int nt = chunk % ntc;
    const int m0 = mt << 7, n0 = nt << 7;

    const short* asrc = Ab + (size_t)(m0 + w * 32 + (lane >> 3)) * K + ((lane & 7) << 3);
    const short* bsrc = Bw + (size_t)(n0 + w * 32 + (lane >> 3)) * K + ((lane & 7) << 3);
    short* adst = &Asb[w * 32 * 64 + lane * 8];
    short* bdst = &Bsb[w * 32 * 64 + lane * 8];

    f32x4 acc[4][4];
#pragma unroll
    for (int m = 0; m < 4; ++m)
#pragma unroll
        for (int n = 0; n < 4; ++n) acc[m][n] = (f32x4){0, 0, 0, 0};

    for (int k0 = 0; k0 < K; k0 += 64) {
        __syncthreads();
#pragma unroll
        for (int i = 0; i < 4; ++i) {
            async16(adst + i * 512, asrc + (size_t)i * 8 * K + k0);
            async16(bdst + i * 512, bsrc + (size_t)i * 8 * K + k0);
        }
        __syncthreads();
#pragma unroll
        for (int kk = 0; kk < 2; ++kk) {
            short8 af[4], bfr[4];
#pragma unroll
            for (int m = 0; m < 4; ++m)
                af[m] = *reinterpret_cast<const short8*>(&Asb[(wr*64 + m*16 + ln)*64 + kk*32 + lh*8]);
#pragma unroll
            for (int n = 0; n < 4; ++n)
                bfr[n] = *reinterpret_cast<const short8*>(&Bsb[(wc*64 + n*16 + ln)*64 + kk*32 + lh*8]);
#pragma unroll
            for (int m = 0; m < 4; ++m)
#pragma unroll
                for (int n = 0; n < 4; ++n)
                    acc[m][n] = MFMA16(af[m], bfr[n], acc[m][n]);
        }
    }
#pragma unroll
    for (int n = 0; n < 4; ++n) {
        const int col = n0 + wc * 64 + n * 16 + ln;
        const float bv = bias[col];
#pragma unroll
        for (int m = 0; m < 4; ++m)
#pragma unroll
            for (int q = 0; q < 4; ++q) {
                const int row = m0 + wr * 64 + m * 16 + lh * 4 + q;
                Cb[(size_t)row * N + col] = f2bs(fmaxf(acc[m][n][q] + bv, 0.f));
            }
    }
}

// ---------------- clf3: [M,1024] bf16 -> time_logits [M,2] --------------------------------
__global__ __launch_bounds__(256) void clf3_kernel(const short* __restrict__ h2b,
    const float* __restrict__ w3, const float* __restrict__ b3, float* __restrict__ TL)
{
    const int lane = threadIdx.x & 63;
    const int w = threadIdx.x >> 6;
    const size_t r = (size_t)blockIdx.x * 4 + w;
    const short* hr = h2b + r * 1024;
    float a0 = 0.f, a1 = 0.f;
#pragma unroll
    for (int half = 0; half < 2; ++half) {
        const int k = half * 512 + lane * 8;
        short8 hv = *(const short8*)&hr[k];
#pragma unroll
        for (int u = 0; u < 8; ++u) {
            const float hf = bf2f(hv[u]);
            a0 = fmaf(hf, w3[k + u], a0);
            a1 = fmaf(hf, w3[1024 + k + u], a1);
        }
    }
    for (int off = 32; off; off >>= 1) { a0 += __shfl_xor(a0, off); a1 += __shfl_xor(a1, off); }
    if (lane == 0) {
        TL[r * 2 + 0] = a0 + b3[0];
        TL[r * 2 + 1] = a1 + b3[1];
    }
}

__global__ void logits_kernel(const float* __restrict__ TL, float* __restrict__ out)
{
    const int tid = threadIdx.x;
    if (tid >= 128) return;
    const int b = tid >> 1, o = tid & 1;
    float s = 0.f;
    for (int t = 0; t < T_STEPS; ++t) s += TL[((size_t)b * T_STEPS + t) * 2 + o];
    out[b * 2 + o] = s * (1.0f / 256.0f);
}

extern "C" void kernel_launch(void* const* d_in, const int* in_sizes, int n_in,
                              void* d_out, int out_size, void* d_ws, size_t ws_size,
                              hipStream_t stream)
{
    const float* x       = (const float*)d_in[0];
    const float* embed_w = (const float*)d_in[1];
    const float* embed_b = (const float*)d_in[2];
    const float* w_ih    = (const float*)d_in[3];
    const float* w_hh    = (const float*)d_in[4];
    const float* b_ih    = (const float*)d_in[5];
    const float* b_hh    = (const float*)d_in[6];
    const float* q1w = (const float*)d_in[7],  *q1b = (const float*)d_in[8];
    const float* q2w = (const float*)d_in[9],  *q2b = (const float*)d_in[10];
    const float* q3w = (const float*)d_in[11], *q3b = (const float*)d_in[12];
    const float* k1w = (const float*)d_in[13], *k1b = (const float*)d_in[14];
    const float* k2w = (const float*)d_in[15], *k2b = (const float*)d_in[16];
    const float* k3w = (const float*)d_in[17], *k3b = (const float*)d_in[18];
    const float* gate_bias = (const float*)d_in[19];
    const float* c1w = (const float*)d_in[20], *c1b = (const float*)d_in[21];
    const float* c2w = (const float*)d_in[22], *c2b = (const float*)d_in[23];
    const float* c3w = (const float*)d_in[24], *c3b = (const float*)d_in[25];
    const float* pw  = (const float*)d_in[26], *pb  = (const float*)d_in[27];

    float* out       = (float*)d_out;
    float* logits    = out;
    float* matrices  = out + MAT_OFF;
    float* TL        = out + TL_OFF;
    float* predicted = out + PRED_OFF;
    float* xcopy     = out + XC_OFF;

    float* ws   = (float*)d_ws;
    float* avec = ws;
    float* cvec = ws + 192;
    short* wsw  = (short*)((char*)d_ws + WSW_BYTE_OFF);
    short* c1wb = (short*)((char*)d_ws + C1WB_BYTE);
    short* c2wb = (short*)((char*)d_ws + C2WB_BYTE);
    short* h1b  = (short*)((char*)d_ws + H1B_BYTE);
    short* h2b  = (short*)((char*)d_ws + H2B_BYTE);

    const int use_mb16 = (ws_size >= MB16_BYTE + 134217728ULL) ? 1 : 0;
    short* mb16 = use_mb16 ? (short*)((char*)d_ws + MB16_BYTE) : (short*)d_ws;

    precompute_kernel<<<1, 256, 0, stream>>>(w_ih, embed_w, embed_b, b_ih, avec, cvec);

    // single merged fp32->bf16 conversion launch (9 segments, 10332 blocks)
    tobf16_all_kernel<<<10332, 256, 0, stream>>>(
        w_hh, q1w, k1w, q2w, k2w, q3w, k3w, c1w, c2w, wsw, c1wb, c2wb);

    scan_kernel<<<B_BATCH, 512, 0, stream>>>(x, b_hh, avec, cvec, wsw,
        q1b, q2b, q3b, k1b, k2b, k3b, gate_bias, pw, pb, matrices, predicted,
        xcopy, mb16, use_mb16);

    const int Mtot = B_BATCH * T_STEPS;   // 16384
    if (use_mb16) {
        gemm2_kernel<<<(Mtot / 128) * (2048 / 128), 256, 0, stream>>>(
            mb16, c1wb, c1b, h1b, Mtot, 2048, 4096);
    } else {
        gemm1_kernel<<<(Mtot / 128) * (2048 / 128), 256, 0, stream>>>(
            matrices, c1wb, c1b, h1b, Mtot, 2048, 4096);
    }
    gemm2_kernel<<<(Mtot / 128) * (1024 / 128), 256, 0, stream>>>(
        h1b, c2wb, c2b, h2b, Mtot, 1024, 2048);
    clf3_kernel<<<Mtot / 4, 256, 0, stream>>>(h2b, c3w, c3b, TL);
    logits_kernel<<<1, 128, 0, stream>>>(TL, logits);
}

// Round 13
// 2706.733 us; speedup vs baseline: 1.0099x; 1.0099x over previous
//
#include <hip/hip_runtime.h>
#include <hip/hip_bf16.h>
#include <math.h>

#define B_BATCH 64
#define T_STEPS 256
#define C_COMP  64

// ws layout: floats [0..191] avec, [192..383] cvec; byte 2048+ : scan bf16 weights
#define WSW_BYTE_OFF 2048
#define WHH_OFF 0
#define Q1_OFF 12288
#define K1_OFF 20480
#define Q2_OFF 28672
#define K2_OFF 45056
#define Q3_OFF 61440
#define K3_OFF 77824
// classifier scratch (bytes)
#define C1WB_BYTE 262144
#define C2WB_BYTE 17039360
#define H1B_BYTE  21233664
#define H2B_BYTE  88342528
#define MB16_BYTE 121896960ULL

// output offsets (floats)
#define MAT_OFF  128
#define TL_OFF   67108992
#define PRED_OFF 67141760
#define XC_OFF   68186240

// LDS strides
#define GST 196   // gates f32
#define HS  68    // h32 f32
#define TS  68    // tf f32
#define GBS 68    // gbias f32

typedef __attribute__((ext_vector_type(8))) short short8;
typedef __attribute__((ext_vector_type(4))) float f32x4;
#define MFMA16(a,b,c) __builtin_amdgcn_mfma_f32_16x16x32_bf16(a,b,c,0,0,0)

__device__ __forceinline__ float fsigm(float v) {
    return __builtin_amdgcn_rcpf(1.0f + __expf(-v));
}
__device__ __forceinline__ float ftanh(float v) {
    return 1.0f - 2.0f * __builtin_amdgcn_rcpf(__expf(2.0f * v) + 1.0f);
}
__device__ __forceinline__ short f2bs(float f) {  // RNE f32->bf16 bits
    unsigned u = __float_as_uint(f);
    u += 0x7fffu + ((u >> 16) & 1u);
    return (short)(u >> 16);
}
__device__ __forceinline__ float bf2f(short s) {
    return __uint_as_float(((unsigned)(unsigned short)s) << 16);
}
// packed bf16x2 via known-good bit-manip RNE (lo16 = a, hi16 = b)
__device__ __forceinline__ unsigned pk2(float a, float b) {
    return (unsigned)(unsigned short)f2bs(a) | ((unsigned)(unsigned short)f2bs(b) << 16);
}
// LDS-only barrier (no vmcnt drain; in-loop global stores have no in-kernel consumer)
__device__ __forceinline__ void bar_lds() {
    asm volatile("s_waitcnt lgkmcnt(0)" ::: "memory");
    __builtin_amdgcn_s_barrier();
}
__device__ __forceinline__ int xorr(int row) { return ((row >> 1) & 7) << 3; }

__device__ __forceinline__ void async16(void* lds, const void* g) {
    __builtin_amdgcn_global_load_lds((const __attribute__((address_space(1))) void*)g,
                                     (__attribute__((address_space(3))) void*)lds, 16, 0, 0);
}

// ---------------- precompute rank-1 embedding+input path --------------------------------
__global__ void precompute_kernel(const float* __restrict__ w_ih,
                                  const float* __restrict__ embed_w,
                                  const float* __restrict__ embed_b,
                                  const float* __restrict__ b_ih,
                                  float* __restrict__ avec, float* __restrict__ cvec)
{
    int g = threadIdx.x;
    if (g < 192) {
        float a = 0.f, c = 0.f;
        for (int e = 0; e < 32; ++e) {
            float w = w_ih[g * 32 + e];
            a += w * embed_w[e];
            c += w * embed_b[e];
        }
        avec[g] = a;
        cvec[g] = c + b_ih[g];
    }
}

// all fp32->bf16 weight conversions in ONE launch; 1024 elems per block (256 thr x 4)
__global__ __launch_bounds__(256) void tobf16_all_kernel(
    const float* __restrict__ s_whh,
    const float* __restrict__ s_q1, const float* __restrict__ s_k1,
    const float* __restrict__ s_q2, const float* __restrict__ s_k2,
    const float* __restrict__ s_q3, const float* __restrict__ s_k3,
    const float* __restrict__ s_c1, const float* __restrict__ s_c2,
    short* __restrict__ wsw, short* __restrict__ c1wb, short* __restrict__ c2wb)
{
    int bb = blockIdx.x;
    const float* src; short* dst; int n;
    if      (bb < 12)   { src = s_whh; dst = wsw + WHH_OFF; n = 12288;            }
    else if (bb < 20)   { src = s_q1;  dst = wsw + Q1_OFF;  n = 8192;  bb -= 12;  }
    else if (bb < 28)   { src = s_k1;  dst = wsw + K1_OFF;  n = 8192;  bb -= 20;  }
    else if (bb < 44)   { src = s_q2;  dst = wsw + Q2_OFF;  n = 16384; bb -= 28;  }
    else if (bb < 60)   { src = s_k2;  dst = wsw + K2_OFF;  n = 16384; bb -= 44;  }
    else if (bb < 76)   { src = s_q3;  dst = wsw + Q3_OFF;  n = 16384; bb -= 60;  }
    else if (bb < 92)   { src = s_k3;  dst = wsw + K3_OFF;  n = 16384; bb -= 76;  }
    else if (bb < 8284) { src = s_c1;  dst = c1wb;          n = 8388608; bb -= 92; }
    else                { src = s_c2;  dst = c2wb;          n = 2097152; bb -= 8284; }
    const int i = bb * 1024 + threadIdx.x * 4;
    if (i < n) {
        float4 v = *reinterpret_cast<const float4*>(&src[i]);
        uint2 p;
        p.x = pk2(v.x, v.y);
        p.y = pk2(v.z, v.w);
        *reinterpret_cast<uint2*>(&dst[i]) = p;
    }
}

// swapped-operand MLP layer: wave computes strips s0,s1 x all 4 row-groups.
// mfma(W_frag, act_frag): lane holds act-row (g*16+ln), 4 consecutive out-cols -> packed b64 stores.
template<int KST, int AST, bool RELU>
__device__ __forceinline__ void two_strip_sw(
    const short* __restrict__ A,
    const short8* __restrict__ B0, const short8* __restrict__ B1,
    const f32x4 bias0, const f32x4 bias1,
    short* __restrict__ outb, const int s0, const int s1, const int ln, const int lh)
{
    f32x4 acc0[4], acc1[4];
#pragma unroll
    for (int g = 0; g < 4; ++g) { acc0[g] = bias0; acc1[g] = bias1; }
#pragma unroll
    for (int kk = 0; kk < KST; ++kk)
#pragma unroll
        for (int g = 0; g < 4; ++g) {
            const int row = g * 16 + ln;
            short8 a = *(const short8*)&A[row * AST + ((kk * 32 + lh * 8) ^ xorr(row))];
            acc0[g] = MFMA16(B0[kk], a, acc0[g]);
            acc1[g] = MFMA16(B1[kk], a, acc1[g]);
        }
#pragma unroll
    for (int g = 0; g < 4; ++g) {
        const int row = g * 16 + ln;
        f32x4 v0 = acc0[g], v1 = acc1[g];
        if (RELU) {
#pragma unroll
            for (int q = 0; q < 4; ++q) { v0[q] = fmaxf(v0[q], 0.f); v1[q] = fmaxf(v1[q], 0.f); }
        }
        uint2 p0, p1;
        p0.x = pk2(v0[0], v0[1]); p0.y = pk2(v0[2], v0[3]);
        p1.x = pk2(v1[0], v1[1]); p1.y = pk2(v1[2], v1[3]);
        *(uint2*)&outb[row * 128 + ((s0 * 16 + lh * 4) ^ xorr(row))] = p0;
        *(uint2*)&outb[row * 128 + ((s1 * 16 + lh * 4) ^ xorr(row))] = p1;
    }
}

// ---------------- the scan: one block (8 waves) per batch, 8 short phases ----------------
__global__ __launch_bounds__(512) void scan_kernel(
    const float* __restrict__ x, const float* __restrict__ b_hh,
    const float* __restrict__ avec, const float* __restrict__ cvec,
    const short* __restrict__ wsw,
    const float* __restrict__ q1b, const float* __restrict__ q2b, const float* __restrict__ q3b,
    const float* __restrict__ k1b, const float* __restrict__ k2b, const float* __restrict__ k3b,
    const float* __restrict__ gate_bias,
    const float* __restrict__ pred_w, const float* __restrict__ pred_b,
    float* __restrict__ matrices, float* __restrict__ predicted,
    float* __restrict__ xcopy,
    short* __restrict__ mb16, const int use_mb16)
{
    __shared__ __align__(16) short hb  [64 * 64];   // post-BTP h (F2 -> P1)
    __shared__ __align__(16) short hbN [64 * 64];   // post-GRU h (P2 -> L1)
    __shared__ __align__(16) short hbT [64 * 64];   // post-GRU h^T (P2 -> F2)
    __shared__ __align__(16) float h32 [64 * HS];   // fp32 post-BTP h (F2 -> P2 hold / predictor)
    __shared__ __align__(16) short qf  [64 * 128];
    __shared__ __align__(16) short kf  [64 * 128];
    __shared__ __align__(16) float gbias_s[64 * GBS];
    __shared__ __align__(16) char arena[65536];
    // small arrays: explicitly 16B-aligned — f32x4 reads below require it
    __shared__ __align__(16) float avec_s[192];
    __shared__ __align__(16) float cvec_s[192];
    __shared__ __align__(16) float bhh_s[192];
    __shared__ __align__(16) float pw_s[64];
    __shared__ __align__(16) float xrow[64];
    __shared__ __align__(16) float red[8];

    float* gates = (float*)arena;                   // [64][196] f32  P1->P2
    short* act2q = (short*)arena;                   // [64][128] swz  L2->L3
    short* act2k = (short*)(arena + 16384);
    short* act1q = (short*)(arena + 32768);         // L1->L2
    short* act1k = (short*)(arena + 49152);
    float* tf    = (float*)arena;                   // [64][68] f32   E->F1
    short* tb    = (short*)(arena + 20480);         // [64][64] swz   F1->F2

    const int tid = threadIdx.x;
    const int b = blockIdx.x;
    const int w = tid >> 6, lane = tid & 63;
    const int ln = lane & 15, lh = lane >> 4;
    const int path = w >> 2;                        // MLP: 0 = q, 1 = k
    const int wq = w & 3;

    for (int i = tid; i < 64 * 64; i += 512) { hb[i] = 0; hbN[i] = 0; hbT[i] = 0; }
    for (int i = tid; i < 64 * HS; i += 512) h32[i] = 0.f;
    for (int i = tid; i < 4096; i += 512)
        gbias_s[(i >> 6) * GBS + (i & 63)] = gate_bias[i];
    if (tid < 192) { avec_s[tid] = avec[tid]; cvec_s[tid] = cvec[tid]; bhh_s[tid] = b_hh[tid]; }
    if (tid < 64) { pw_s[tid] = pred_w[tid]; xrow[tid] = x[(size_t)b * T_STEPS * 64 + tid]; }
    const float pbv = pred_b[0];

    // ---- weight fragments (A-operand = weight rows = output cols), constant across t ----
    const short* whh_b = wsw + WHH_OFF;
    const short* l1w = path ? wsw + K1_OFF : wsw + Q1_OFF;
    const short* l2w = path ? wsw + K2_OFF : wsw + Q2_OFF;
    const short* l3w = path ? wsw + K3_OFF : wsw + Q3_OFF;
    const float* l1b = path ? k1b : q1b;
    const float* l2b = path ? k2b : q2b;
    const float* l3b = path ? k3b : q3b;

    short8 Bg[2][2], B1[2][2], B2[2][4], B3[2][4];
#pragma unroll
    for (int kk = 0; kk < 2; ++kk)
        Bg[0][kk] = *(const short8*)&whh_b[(w * 16 + ln) * 64 + kk * 32 + lh * 8];
    if (w < 4) {
#pragma unroll
        for (int kk = 0; kk < 2; ++kk)
            Bg[1][kk] = *(const short8*)&whh_b[((w + 8) * 16 + ln) * 64 + kk * 32 + lh * 8];
    }
#pragma unroll
    for (int s = 0; s < 2; ++s) {
        const int strip = wq + s * 4;
#pragma unroll
        for (int kk = 0; kk < 2; ++kk)
            B1[s][kk] = *(const short8*)&l1w[(strip * 16 + ln) * 64 + kk * 32 + lh * 8];
#pragma unroll
        for (int kk = 0; kk < 4; ++kk) {
            B2[s][kk] = *(const short8*)&l2w[(strip * 16 + ln) * 128 + kk * 32 + lh * 8];
            B3[s][kk] = *(const short8*)&l3w[(strip * 16 + ln) * 128 + kk * 32 + lh * 8];
        }
    }
    // per-lane bias vectors (4 consecutive out-cols each); global, 16B-aligned offsets
    const f32x4 b1v0 = *(const f32x4*)&l1b[wq * 16 + lh * 4];
    const f32x4 b1v1 = *(const f32x4*)&l1b[(wq + 4) * 16 + lh * 4];
    const f32x4 b2v0 = *(const f32x4*)&l2b[wq * 16 + lh * 4];
    const f32x4 b2v1 = *(const f32x4*)&l2b[(wq + 4) * 16 + lh * 4];
    const f32x4 b3v0 = *(const f32x4*)&l3b[wq * 16 + lh * 4];
    const f32x4 b3v1 = *(const f32x4*)&l3b[(wq + 4) * 16 + lh * 4];
    __syncthreads();

    for (int t = 0; t < T_STEPS; ++t) {
        // ===== P1: x prefetch, predictor(t-1), gates = h @ w_hh^T (swapped, packed) =====
        float xnext = 0.f;
        if (tid < 64 && t + 1 < T_STEPS)
            xnext = x[((size_t)b * T_STEPS + t + 1) * 64 + tid];
        if (t > 0) {
            const int c = tid >> 3, j0 = (tid & 7) * 8;
            f32x4 h0 = *(const f32x4*)&h32[c * HS + j0];
            f32x4 h1 = *(const f32x4*)&h32[c * HS + j0 + 4];
            f32x4 w0 = *(const f32x4*)&pw_s[j0];
            f32x4 w1 = *(const f32x4*)&pw_s[j0 + 4];
            float p = 0.f;
#pragma unroll
            for (int q = 0; q < 4; ++q) p = fmaf(h0[q], w0[q], fmaf(h1[q], w1[q], p));
            p += __shfl_xor(p, 1); p += __shfl_xor(p, 2); p += __shfl_xor(p, 4);
            if ((lane & 7) == 0)
                predicted[((size_t)b * (T_STEPS - 1) + (t - 1)) * 64 + c] = p + pbv;
        }
        {
            f32x4 accA[4], accB[4];
            const f32x4 bhA = *(const f32x4*)&bhh_s[w * 16 + lh * 4];
#pragma unroll
            for (int g = 0; g < 4; ++g) accA[g] = bhA;
            if (w < 4) {
                const f32x4 bhB = *(const f32x4*)&bhh_s[(w + 8) * 16 + lh * 4];
#pragma unroll
                for (int g = 0; g < 4; ++g) accB[g] = bhB;
            }
#pragma unroll
            for (int kk = 0; kk < 2; ++kk)
#pragma unroll
                for (int g = 0; g < 4; ++g) {
                    const int row = g * 16 + ln;
                    short8 hv = *(const short8*)&hb[row * 64 + ((kk * 32 + lh * 8) ^ xorr(row))];
                    accA[g] = MFMA16(Bg[0][kk], hv, accA[g]);
                    if (w < 4) accB[g] = MFMA16(Bg[1][kk], hv, accB[g]);
                }
#pragma unroll
            for (int g = 0; g < 4; ++g)
                *(f32x4*)&gates[(g * 16 + ln) * GST + w * 16 + lh * 4] = accA[g];
            if (w < 4) {
#pragma unroll
                for (int g = 0; g < 4; ++g)
                    *(f32x4*)&gates[(g * 16 + ln) * GST + (w + 8) * 16 + lh * 4] = accB[g];
            }
        }
        bar_lds();

        // ===== P2: GRU elementwise (vectorized LDS) -> h32, hbN, hbT =====
        {
            const int c = tid >> 3, j0 = (tid & 7) * 8;
            const float xv = xrow[c];
            unsigned pk[4];
#pragma unroll
            for (int h2 = 0; h2 < 2; ++h2) {
                const int jh = j0 + h2 * 4;
                f32x4 gr4 = *(const f32x4*)&gates[c * GST + jh];
                f32x4 gz4 = *(const f32x4*)&gates[c * GST + 64 + jh];
                f32x4 gn4 = *(const f32x4*)&gates[c * GST + 128 + jh];
                f32x4 ho4 = *(const f32x4*)&h32[c * HS + jh];
                f32x4 ar4 = *(const f32x4*)&avec_s[jh];
                f32x4 az4 = *(const f32x4*)&avec_s[64 + jh];
                f32x4 an4 = *(const f32x4*)&avec_s[128 + jh];
                f32x4 cr4 = *(const f32x4*)&cvec_s[jh];
                f32x4 cz4 = *(const f32x4*)&cvec_s[64 + jh];
                f32x4 cn4 = *(const f32x4*)&cvec_s[128 + jh];
                f32x4 hn4;
#pragma unroll
                for (int q = 0; q < 4; ++q) {
                    const float r = fsigm(gr4[q] + fmaf(xv, ar4[q], cr4[q]));
                    const float z = fsigm(gz4[q] + fmaf(xv, az4[q], cz4[q]));
                    const float n = ftanh(fmaf(r, gn4[q], fmaf(xv, an4[q], cn4[q])));
                    hn4[q] = fmaf(z, ho4[q] - n, n);
                }
                *(f32x4*)&h32[c * HS + jh] = hn4;
                const unsigned plo = pk2(hn4[0], hn4[1]);
                const unsigned phi = pk2(hn4[2], hn4[3]);
                pk[h2 * 2] = plo; pk[h2 * 2 + 1] = phi;
                // transposed scalar stores (bf16 halves of the packed words)
                hbT[(jh + 0) * 64 + (c ^ xorr(jh + 0))] = (short)plo;
                hbT[(jh + 1) * 64 + (c ^ xorr(jh + 1))] = (short)(plo >> 16);
                hbT[(jh + 2) * 64 + (c ^ xorr(jh + 2))] = (short)phi;
                hbT[(jh + 3) * 64 + (c ^ xorr(jh + 3))] = (short)(phi >> 16);
            }
            uint4 pv; pv.x = pk[0]; pv.y = pk[1]; pv.z = pk[2]; pv.w = pk[3];
            *(uint4*)&hbN[c * 64 + (j0 ^ xorr(c))] = pv;
        }
        bar_lds();

        // ===== L1-L3: q / k MLPs (swapped, packed stores) =====
        two_strip_sw<2, 64,  true >(hbN, B1[0], B1[1], b1v0, b1v1,
                                    path ? act1k : act1q, wq, wq + 4, ln, lh);
        bar_lds();
        two_strip_sw<4, 128, true >(path ? act1k : act1q, B2[0], B2[1], b2v0, b2v1,
                                    path ? act2k : act2q, wq, wq + 4, ln, lh);
        bar_lds();
        two_strip_sw<4, 128, false>(path ? act2k : act2q, B3[0], B3[1], b3v0, b3v1,
                                    path ? kf : qf, wq, wq + 4, ln, lh);
        bar_lds();

        // ===== E: tf = Q @ K^T via mfma(K_frag, Q_frag) -> packed f32x4 stores =====
        {
            const int qg = w & 3, kg = (w >> 2) * 2;
            f32x4 ac0 = {0,0,0,0}, ac1 = {0,0,0,0};
#pragma unroll
            for (int kk = 0; kk < 4; ++kk) {
                const int rq = qg * 16 + ln, rk0 = kg * 16 + ln, rk1 = (kg + 1) * 16 + ln;
                short8 bq = *(const short8*)&qf[rq * 128 + ((kk * 32 + lh * 8) ^ xorr(rq))];
                short8 a0 = *(const short8*)&kf[rk0 * 128 + ((kk * 32 + lh * 8) ^ xorr(rk0))];
                short8 a1 = *(const short8*)&kf[rk1 * 128 + ((kk * 32 + lh * 8) ^ xorr(rk1))];
                ac0 = MFMA16(a0, bq, ac0);
                ac1 = MFMA16(a1, bq, ac1);
            }
            const int qrow = qg * 16 + ln;
            *(f32x4*)&tf[qrow * TS + kg * 16 + lh * 4]       = ac0;
            *(f32x4*)&tf[qrow * TS + (kg + 1) * 16 + lh * 4] = ac1;
            float ss = 0.f;
#pragma unroll
            for (int q = 0; q < 4; ++q)
                ss = fmaf(ac0[q], ac0[q], fmaf(ac1[q], ac1[q], ss));
#pragma unroll
            for (int off = 1; off < 64; off <<= 1) ss += __shfl_xor(ss, off);
            if (lane == 0) red[w] = ss;
            if (tid < 64 && t + 1 < T_STEPS) {
                xrow[tid] = xnext;
                // output 5 = x[:,1:,:] — stored HERE (vmcnt for the load already paid by
                // the 5-phase distance from P1; placing this in P1 cost +40us in r12)
                xcopy[((size_t)b * (T_STEPS - 1) + t) * 64 + tid] = xnext;
            }
        }
        bar_lds();

        // ===== F1: normalize + gate -> fp32 matrices + (opt) mb16 + tb =====
        {
            const int ci = tid >> 3, j0 = (tid & 7) * 8;
            const float ssum = red[0]+red[1]+red[2]+red[3]+red[4]+red[5]+red[6]+red[7];
            const float inv = __builtin_amdgcn_rsqf(ssum);
            const size_t mbase = ((size_t)b * T_STEPS + t) * 4096;
            unsigned pk[4];
#pragma unroll
            for (int h2 = 0; h2 < 2; ++h2) {
                const int jh = j0 + h2 * 4;
                f32x4 t4  = *(const f32x4*)&tf[ci * TS + jh];
                f32x4 gb4 = *(const f32x4*)&gbias_s[ci * GBS + jh];
                f32x4 v4;
#pragma unroll
                for (int q = 0; q < 4; ++q) {
                    const float tv = t4[q] * inv;
                    const float g = fsigm(fabsf(tv) + gb4[q]);
                    v4[q] = tv * g;
                }
                pk[h2 * 2]     = pk2(v4[0], v4[1]);
                pk[h2 * 2 + 1] = pk2(v4[2], v4[3]);
                // fp32 output written directly
                *(f32x4*)&matrices[mbase + ci * 64 + jh] = v4;
            }
            uint4 pv; pv.x = pk[0]; pv.y = pk[1]; pv.z = pk[2]; pv.w = pk[3];
            if (use_mb16)
                *(uint4*)&mb16[mbase + ci * 64 + j0] = pv;
            *(uint4*)&tb[ci * 64 + (j0 ^ xorr(ci))] = pv;
        }
        bar_lds();

        // ===== F2: h_new = T @ h_post via mfma(hbT_frag, tb_frag) -> h32, hb (packed) =====
        {
            const int jg = w & 3, ig = (w >> 2) * 2;
            f32x4 hc0 = {0,0,0,0}, hc1 = {0,0,0,0};
#pragma unroll
            for (int kk = 0; kk < 2; ++kk) {
                const int rj = jg * 16 + ln, ri0 = ig * 16 + ln, ri1 = (ig + 1) * 16 + ln;
                short8 bt = *(const short8*)&tb [rj * 64 + ((kk * 32 + lh * 8) ^ xorr(rj))];
                short8 a0 = *(const short8*)&hbT[ri0 * 64 + ((kk * 32 + lh * 8) ^ xorr(ri0))];
                short8 a1 = *(const short8*)&hbT[ri1 * 64 + ((kk * 32 + lh * 8) ^ xorr(ri1))];
                hc0 = MFMA16(a0, bt, hc0);
                hc1 = MFMA16(a1, bt, hc1);
            }
            const int row = jg * 16 + ln;
            *(f32x4*)&h32[row * HS + ig * 16 + lh * 4]       = hc0;
            *(f32x4*)&h32[row * HS + (ig + 1) * 16 + lh * 4] = hc1;
            uint2 p0, p1;
            p0.x = pk2(hc0[0], hc0[1]); p0.y = pk2(hc0[2], hc0[3]);
            p1.x = pk2(hc1[0], hc1[1]); p1.y = pk2(hc1[2], hc1[3]);
            *(uint2*)&hb[row * 64 + ((ig * 16 + lh * 4) ^ xorr(row))]       = p0;
            *(uint2*)&hb[row * 64 + (((ig + 1) * 16 + lh * 4) ^ xorr(row))] = p1;
        }
        bar_lds();
    }
}

// ---------------- clf1 fallback: A fp32 (reg-convert) x B bf16 -> bf16 C ------------------
__global__ __launch_bounds__(256) void gemm1_kernel(
    const float* __restrict__ A, const short* __restrict__ Bw,
    const float* __restrict__ bias, short* __restrict__ Cb,
    const int M, const int N, const int K)
{
    __shared__ __align__(16) short Asb[128 * 64];
    __shared__ __align__(16) short Bsb[128 * 64];
    const int tid = threadIdx.x;
    const int w = tid >> 6, lane = tid & 63;
    const int ln = lane & 15, lh = lane >> 4;
    const int wr = w >> 1, wc = w & 1;

    const int ntc = N >> 7;
    const int g = blockIdx.x;
    const int xcd = g & 7, chunk = g >> 3;
    const int mt = xcd * ((M >> 7) >> 3) + chunk / ntc;
    const int nt = chunk % ntc;
    const int m0 = mt << 7, n0 = nt << 7;

    const int ar = tid >> 1;
    const int ac = (tid & 1) << 5;
    const short* bsrc = Bw + (size_t)(n0 + w * 32 + (lane >> 3)) * K + ((lane & 7) << 3);
    short* bdst = &Bsb[w * 32 * 64 + lane * 8];

    f32x4 acc[4][4];
#pragma unroll
    for (int m = 0; m < 4; ++m)
#pragma unroll
        for (int n = 0; n < 4; ++n) acc[m][n] = (f32x4){0, 0, 0, 0};

    for (int k0 = 0; k0 < K; k0 += 64) {
        const float* arow = A + (size_t)(m0 + ar) * K + k0 + ac;
        float4 av[8];
#pragma unroll
        for (int i = 0; i < 8; ++i) av[i] = *reinterpret_cast<const float4*>(arow + i * 4);
        short8 cv[4];
#pragma unroll
        for (int i = 0; i < 4; ++i) {
            cv[i][0] = f2bs(av[2*i].x);   cv[i][1] = f2bs(av[2*i].y);
            cv[i][2] = f2bs(av[2*i].z);   cv[i][3] = f2bs(av[2*i].w);
            cv[i][4] = f2bs(av[2*i+1].x); cv[i][5] = f2bs(av[2*i+1].y);
            cv[i][6] = f2bs(av[2*i+1].z); cv[i][7] = f2bs(av[2*i+1].w);
        }
        __syncthreads();
#pragma unroll
        for (int i = 0; i < 4; ++i)
            *reinterpret_cast<short8*>(&Asb[ar * 64 + ac + i * 8]) = cv[i];
#pragma unroll
        for (int i = 0; i < 4; ++i)
            async16(bdst + i * 512, bsrc + (size_t)i * 8 * K + k0);
        __syncthreads();
#pragma unroll
        for (int kk = 0; kk < 2; ++kk) {
            short8 af[4], bfr[4];
#pragma unroll
            for (int m = 0; m < 4; ++m)
                af[m] = *reinterpret_cast<const short8*>(&Asb[(wr*64 + m*16 + ln)*64 + kk*32 + lh*8]);
#pragma unroll
            for (int n = 0; n < 4; ++n)
                bfr[n] = *reinterpret_cast<const short8*>(&Bsb[(wc*64 + n*16 + ln)*64 + kk*32 + lh*8]);
#pragma unroll
            for (int m = 0; m < 4; ++m)
#pragma unroll
                for (int n = 0; n < 4; ++n)
                    acc[m][n] = MFMA16(af[m], bfr[n], acc[m][n]);
        }
    }
#pragma unroll
    for (int n = 0; n < 4; ++n) {
        const int col = n0 + wc * 64 + n * 16 + ln;
        const float bv = bias[col];
#pragma unroll
        for (int m = 0; m < 4; ++m)
#pragma unroll
            for (int q = 0; q < 4; ++q) {
                const int row = m0 + wr * 64 + m * 16 + lh * 4 + q;
                Cb[(size_t)row * N + col] = f2bs(fmaxf(acc[m][n][q] + bv, 0.f));
            }
    }
}

// ---------------- bf16 x bf16 GEMM via gload_lds (clf1 / clf2) ----------------------------
__global__ __launch_bounds__(256) void gemm2_kernel(
    const short* __restrict__ Ab, const short* __restrict__ Bw,
    const float* __restrict__ bias, short* __restrict__ Cb,
    const int M, const int N, const int K)
{
    __shared__ __align__(16) short Asb[128 * 64];
    __shared__ __align__(16) short Bsb[128 * 64];
    const int tid = threadIdx.x;
    const int w = tid >> 6, lane = tid & 63;
    const int ln = lane & 15, lh = lane >> 4;
    const int wr = w >> 1, wc = w & 1;

    const int ntc = N >> 7;
    const int g = blockIdx.x;
    const int xcd = g & 7, chunk = g >> 3;
    const int mt = xcd * ((M >> 7) >> 3) + chunk / ntc;
    const int nt = chunk % ntc;
    const int m0 = mt << 7, n0 = nt << 7;

    const short* asrc = Ab + (size_t)(m0 + w * 32 + (lane >> 3)) * K + ((lane & 7) << 3);
    const short* bsrc = Bw + (size_t)(n0 + w * 32 + (lane >> 3)) * K + ((lane & 7) << 3);
    short* adst = &Asb[w * 32 * 64 + lane * 8];
    short* bdst = &Bsb[w * 32 * 64 + lane * 8];

    f32x4 acc[4][4];
#pragma unroll
    for (int m = 0; m < 4; ++m)
#pragma unroll
        for (int n = 0; n < 4; ++n) acc[m][n] = (f32x4){0, 0, 0, 0};

    for (int k0 = 0; k0 < K; k0 += 64) {
        __syncthreads();
#pragma unroll
        for (int i = 0; i < 4; ++i) {
            async16(adst + i * 512, asrc + (size_t)i * 8 * K + k0);
            async16(bdst + i * 512, bsrc + (size_t)i * 8 * K + k0);
        }
        __syncthreads();
#pragma unroll
        for (int kk = 0; kk < 2; ++kk) {
            short8 af[4], bfr[4];
#pragma unroll
            for (int m = 0; m < 4; ++m)
                af[m] = *reinterpret_cast<const short8*>(&Asb[(wr*64 + m*16 + ln)*64 + kk*32 + lh*8]);
#pragma unroll
            for (int n = 0; n < 4; ++n)
                bfr[n] = *reinterpret_cast<const short8*>(&Bsb[(wc*64 + n*16 + ln)*64 + kk*32 + lh*8]);
#pragma unroll
            for (int m = 0; m < 4; ++m)
#pragma unroll
                for (int n = 0; n < 4; ++n)
                    acc[m][n] = MFMA16(af[m], bfr[n], acc[m][n]);
        }
    }
#pragma unroll
    for (int n = 0; n < 4; ++n) {
        const int col = n0 + wc * 64 + n * 16 + ln;
        const float bv = bias[col];
#pragma unroll
        for (int m = 0; m < 4; ++m)
#pragma unroll
            for (int q = 0; q < 4; ++q) {
                const int row = m0 + wr * 64 + m * 16 + lh * 4 + q;
                Cb[(size_t)row * N + col] = f2bs(fmaxf(acc[m][n][q] + bv, 0.f));
            }
    }
}

// ---------------- clf3: [M,1024] bf16 -> time_logits [M,2] --------------------------------
__global__ __launch_bounds__(256) void clf3_kernel(const short* __restrict__ h2b,
    const float* __restrict__ w3, const float* __restrict__ b3, float* __restrict__ TL)
{
    const int lane = threadIdx.x & 63;
    const int w = threadIdx.x >> 6;
    const size_t r = (size_t)blockIdx.x * 4 + w;
    const short* hr = h2b + r * 1024;
    float a0 = 0.f, a1 = 0.f;
#pragma unroll
    for (int half = 0; half < 2; ++half) {
        const int k = half * 512 + lane * 8;
        short8 hv = *(const short8*)&hr[k];
#pragma unroll
        for (int u = 0; u < 8; ++u) {
            const float hf = bf2f(hv[u]);
            a0 = fmaf(hf, w3[k + u], a0);
            a1 = fmaf(hf, w3[1024 + k + u], a1);
        }
    }
    for (int off = 32; off; off >>= 1) { a0 += __shfl_xor(a0, off); a1 += __shfl_xor(a1, off); }
    if (lane == 0) {
        TL[r * 2 + 0] = a0 + b3[0];
        TL[r * 2 + 1] = a1 + b3[1];
    }
}

__global__ void logits_kernel(const float* __restrict__ TL, float* __restrict__ out)
{
    const int tid = threadIdx.x;
    if (tid >= 128) return;
    const int b = tid >> 1, o = tid & 1;
    float s = 0.f;
    for (int t = 0; t < T_STEPS; ++t) s += TL[((size_t)b * T_STEPS + t) * 2 + o];
    out[b * 2 + o] = s * (1.0f / 256.0f);
}

extern "C" void kernel_launch(void* const* d_in, const int* in_sizes, int n_in,
                              void* d_out, int out_size, void* d_ws, size_t ws_size,
                              hipStream_t stream)
{
    const float* x       = (const float*)d_in[0];
    const float* embed_w = (const float*)d_in[1];
    const float* embed_b = (const float*)d_in[2];
    const float* w_ih    = (const float*)d_in[3];
    const float* w_hh    = (const float*)d_in[4];
    const float* b_ih    = (const float*)d_in[5];
    const float* b_hh    = (const float*)d_in[6];
    const float* q1w = (const float*)d_in[7],  *q1b = (const float*)d_in[8];
    const float* q2w = (const float*)d_in[9],  *q2b = (const float*)d_in[10];
    const float* q3w = (const float*)d_in[11], *q3b = (const float*)d_in[12];
    const float* k1w = (const float*)d_in[13], *k1b = (const float*)d_in[14];
    const float* k2w = (const float*)d_in[15], *k2b = (const float*)d_in[16];
    const float* k3w = (const float*)d_in[17], *k3b = (const float*)d_in[18];
    const float* gate_bias = (const float*)d_in[19];
    const float* c1w = (const float*)d_in[20], *c1b = (const float*)d_in[21];
    const float* c2w = (const float*)d_in[22], *c2b = (const float*)d_in[23];
    const float* c3w = (const float*)d_in[24], *c3b = (const float*)d_in[25];
    const float* pw  = (const float*)d_in[26], *pb  = (const float*)d_in[27];

    float* out       = (float*)d_out;
    float* logits    = out;
    float* matrices  = out + MAT_OFF;
    float* TL        = out + TL_OFF;
    float* predicted = out + PRED_OFF;
    float* xcopy     = out + XC_OFF;

    float* ws   = (float*)d_ws;
    float* avec = ws;
    float* cvec = ws + 192;
    short* wsw  = (short*)((char*)d_ws + WSW_BYTE_OFF);
    short* c1wb = (short*)((char*)d_ws + C1WB_BYTE);
    short* c2wb = (short*)((char*)d_ws + C2WB_BYTE);
    short* h1b  = (short*)((char*)d_ws + H1B_BYTE);
    short* h2b  = (short*)((char*)d_ws + H2B_BYTE);

    const int use_mb16 = (ws_size >= MB16_BYTE + 134217728ULL) ? 1 : 0;
    short* mb16 = use_mb16 ? (short*)((char*)d_ws + MB16_BYTE) : (short*)d_ws;

    precompute_kernel<<<1, 256, 0, stream>>>(w_ih, embed_w, embed_b, b_ih, avec, cvec);

    // single merged fp32->bf16 conversion launch (9 segments, 10332 blocks)
    tobf16_all_kernel<<<10332, 256, 0, stream>>>(
        w_hh, q1w, k1w, q2w, k2w, q3w, k3w, c1w, c2w, wsw, c1wb, c2wb);

    scan_kernel<<<B_BATCH, 512, 0, stream>>>(x, b_hh, avec, cvec, wsw,
        q1b, q2b, q3b, k1b, k2b, k3b, gate_bias, pw, pb, matrices, predicted,
        xcopy, mb16, use_mb16);

    const int Mtot = B_BATCH * T_STEPS;   // 16384
    if (use_mb16) {
        gemm2_kernel<<<(Mtot / 128) * (2048 / 128), 256, 0, stream>>>(
            mb16, c1wb, c1b, h1b, Mtot, 2048, 4096);
    } else {
        gemm1_kernel<<<(Mtot / 128) * (2048 / 128), 256, 0, stream>>>(
            matrices, c1wb, c1b, h1b, Mtot, 2048, 4096);
    }
    gemm2_kernel<<<(Mtot / 128) * (1024 / 128), 256, 0, stream>>>(
        h1b, c2wb, c2b, h2b, Mtot, 1024, 2048);
    clf3_kernel<<<Mtot / 4, 256, 0, stream>>>(h2b, c3w, c3b, TL);
    logits_kernel<<<1, 128, 0, stream>>>(TL, logits);
}

// Round 14
// 2674.056 us; speedup vs baseline: 1.0222x; 1.0122x over previous
//
#include <hip/hip_runtime.h>
#include <hip/hip_bf16.h>
#include <math.h>

#define B_BATCH 64
#define T_STEPS 256
#define C_COMP  64

// ws layout: floats [0..191] avec, [192..383] cvec; byte 2048+ : scan bf16 weights
#define WSW_BYTE_OFF 2048
#define WHH_OFF 0
#define Q1_OFF 12288
#define K1_OFF 20480
#define Q2_OFF 28672
#define K2_OFF 45056
#define Q3_OFF 61440
#define K3_OFF 77824
// classifier scratch (bytes)
#define C1WB_BYTE 262144
#define C2WB_BYTE 17039360
#define H1B_BYTE  21233664
#define H2B_BYTE  88342528
#define MB16_BYTE 121896960ULL

// output offsets (floats)
#define MAT_OFF  128
#define TL_OFF   67108992
#define PRED_OFF 67141760
#define XC_OFF   68186240

// LDS strides
#define GST 196   // gates f32
#define HS  68    // h32 f32
#define TS  68    // tf f32
#define GBS 68    // gbias f32

typedef __attribute__((ext_vector_type(8))) short short8;
typedef __attribute__((ext_vector_type(4))) float f32x4;
#define MFMA16(a,b,c) __builtin_amdgcn_mfma_f32_16x16x32_bf16(a,b,c,0,0,0)

__device__ __forceinline__ float fsigm(float v) {
    return __builtin_amdgcn_rcpf(1.0f + __expf(-v));
}
__device__ __forceinline__ float ftanh(float v) {
    return 1.0f - 2.0f * __builtin_amdgcn_rcpf(__expf(2.0f * v) + 1.0f);
}
__device__ __forceinline__ short f2bs(float f) {  // RNE f32->bf16 bits
    unsigned u = __float_as_uint(f);
    u += 0x7fffu + ((u >> 16) & 1u);
    return (short)(u >> 16);
}
__device__ __forceinline__ float bf2f(short s) {
    return __uint_as_float(((unsigned)(unsigned short)s) << 16);
}
// packed bf16x2 via known-good bit-manip RNE (lo16 = a, hi16 = b)
__device__ __forceinline__ unsigned pk2(float a, float b) {
    return (unsigned)(unsigned short)f2bs(a) | ((unsigned)(unsigned short)f2bs(b) << 16);
}
// LDS-only barrier (no vmcnt drain; in-loop global stores have no in-kernel consumer)
__device__ __forceinline__ void bar_lds() {
    asm volatile("s_waitcnt lgkmcnt(0)" ::: "memory");
    __builtin_amdgcn_s_barrier();
}
__device__ __forceinline__ int xorr(int row) { return ((row >> 1) & 7) << 3; }

__device__ __forceinline__ void async16(void* lds, const void* g) {
    __builtin_amdgcn_global_load_lds((const __attribute__((address_space(1))) void*)g,
                                     (__attribute__((address_space(3))) void*)lds, 16, 0, 0);
}

// ---------------- precompute rank-1 embedding+input path --------------------------------
__global__ void precompute_kernel(const float* __restrict__ w_ih,
                                  const float* __restrict__ embed_w,
                                  const float* __restrict__ embed_b,
                                  const float* __restrict__ b_ih,
                                  float* __restrict__ avec, float* __restrict__ cvec)
{
    int g = threadIdx.x;
    if (g < 192) {
        float a = 0.f, c = 0.f;
        for (int e = 0; e < 32; ++e) {
            float w = w_ih[g * 32 + e];
            a += w * embed_w[e];
            c += w * embed_b[e];
        }
        avec[g] = a;
        cvec[g] = c + b_ih[g];
    }
}

// all fp32->bf16 weight conversions + x[:,1:,:] copy in ONE launch (10 segments)
__global__ __launch_bounds__(256) void tobf16_all_kernel(
    const float* __restrict__ s_whh,
    const float* __restrict__ s_q1, const float* __restrict__ s_k1,
    const float* __restrict__ s_q2, const float* __restrict__ s_k2,
    const float* __restrict__ s_q3, const float* __restrict__ s_k3,
    const float* __restrict__ s_c1, const float* __restrict__ s_c2,
    short* __restrict__ wsw, short* __restrict__ c1wb, short* __restrict__ c2wb,
    const float* __restrict__ x, float* __restrict__ xcopy)
{
    int bb = blockIdx.x;
    if (bb >= 10332) {   // segment 10: xcopy = x[:,1:,:]  (1020 blocks, float copy)
        bb -= 10332;
        const int i = bb * 1024 + threadIdx.x * 4;
        if (i < B_BATCH * (T_STEPS - 1) * C_COMP) {
            const int b = i / ((T_STEPS - 1) * C_COMP);
            const int r = i - b * (T_STEPS - 1) * C_COMP;
            float4 v = *reinterpret_cast<const float4*>(&x[(size_t)b * (T_STEPS * C_COMP) + C_COMP + r]);
            *reinterpret_cast<float4*>(&xcopy[i]) = v;
        }
        return;
    }
    const float* src; short* dst; int n;
    if      (bb < 12)   { src = s_whh; dst = wsw + WHH_OFF; n = 12288;            }
    else if (bb < 20)   { src = s_q1;  dst = wsw + Q1_OFF;  n = 8192;  bb -= 12;  }
    else if (bb < 28)   { src = s_k1;  dst = wsw + K1_OFF;  n = 8192;  bb -= 20;  }
    else if (bb < 44)   { src = s_q2;  dst = wsw + Q2_OFF;  n = 16384; bb -= 28;  }
    else if (bb < 60)   { src = s_k2;  dst = wsw + K2_OFF;  n = 16384; bb -= 44;  }
    else if (bb < 76)   { src = s_q3;  dst = wsw + Q3_OFF;  n = 16384; bb -= 60;  }
    else if (bb < 92)   { src = s_k3;  dst = wsw + K3_OFF;  n = 16384; bb -= 76;  }
    else if (bb < 8284) { src = s_c1;  dst = c1wb;          n = 8388608; bb -= 92; }
    else                { src = s_c2;  dst = c2wb;          n = 2097152; bb -= 8284; }
    const int i = bb * 1024 + threadIdx.x * 4;
    if (i < n) {
        float4 v = *reinterpret_cast<const float4*>(&src[i]);
        uint2 p;
        p.x = pk2(v.x, v.y);
        p.y = pk2(v.z, v.w);
        *reinterpret_cast<uint2*>(&dst[i]) = p;
    }
}

// swapped-operand MLP layer: wave computes strips s0,s1 x all 4 row-groups.
// mfma(W_frag, act_frag): lane holds act-row (g*16+ln), 4 consecutive out-cols -> packed b64 stores.
template<int KST, int AST, bool RELU>
__device__ __forceinline__ void two_strip_sw(
    const short* __restrict__ A,
    const short8* __restrict__ B0, const short8* __restrict__ B1,
    const f32x4 bias0, const f32x4 bias1,
    short* __restrict__ outb, const int s0, const int s1, const int ln, const int lh)
{
    f32x4 acc0[4], acc1[4];
#pragma unroll
    for (int g = 0; g < 4; ++g) { acc0[g] = bias0; acc1[g] = bias1; }
#pragma unroll
    for (int kk = 0; kk < KST; ++kk)
#pragma unroll
        for (int g = 0; g < 4; ++g) {
            const int row = g * 16 + ln;
            short8 a = *(const short8*)&A[row * AST + ((kk * 32 + lh * 8) ^ xorr(row))];
            acc0[g] = MFMA16(B0[kk], a, acc0[g]);
            acc1[g] = MFMA16(B1[kk], a, acc1[g]);
        }
#pragma unroll
    for (int g = 0; g < 4; ++g) {
        const int row = g * 16 + ln;
        f32x4 v0 = acc0[g], v1 = acc1[g];
        if (RELU) {
#pragma unroll
            for (int q = 0; q < 4; ++q) { v0[q] = fmaxf(v0[q], 0.f); v1[q] = fmaxf(v1[q], 0.f); }
        }
        uint2 p0, p1;
        p0.x = pk2(v0[0], v0[1]); p0.y = pk2(v0[2], v0[3]);
        p1.x = pk2(v1[0], v1[1]); p1.y = pk2(v1[2], v1[3]);
        *(uint2*)&outb[row * 128 + ((s0 * 16 + lh * 4) ^ xorr(row))] = p0;
        *(uint2*)&outb[row * 128 + ((s1 * 16 + lh * 4) ^ xorr(row))] = p1;
    }
}

// ---------------- the scan: one block (8 waves) per batch, 8 short phases ----------------
__global__ __launch_bounds__(512) void scan_kernel(
    const float* __restrict__ x, const float* __restrict__ b_hh,
    const float* __restrict__ avec, const float* __restrict__ cvec,
    const short* __restrict__ wsw,
    const float* __restrict__ q1b, const float* __restrict__ q2b, const float* __restrict__ q3b,
    const float* __restrict__ k1b, const float* __restrict__ k2b, const float* __restrict__ k3b,
    const float* __restrict__ gate_bias,
    const float* __restrict__ pred_w, const float* __restrict__ pred_b,
    float* __restrict__ matrices, float* __restrict__ predicted,
    short* __restrict__ mb16, const int use_mb16)
{
    __shared__ __align__(16) short hb  [64 * 64];   // post-BTP h (F2 -> P1)
    __shared__ __align__(16) short hbN [64 * 64];   // post-GRU h (P2 -> L1)
    __shared__ __align__(16) short hbT [64 * 64];   // post-GRU h^T (P2 -> F2)
    __shared__ __align__(16) float h32 [64 * HS];   // fp32 post-BTP h (F2 -> P2 hold / predictor)
    __shared__ __align__(16) short qf  [64 * 128];
    __shared__ __align__(16) short kf  [64 * 128];
    __shared__ __align__(16) float gbias_s[64 * GBS];
    __shared__ __align__(16) char arena[65536];
    // small arrays: explicitly 16B-aligned — f32x4 reads below require it
    __shared__ __align__(16) float avec_s[192];
    __shared__ __align__(16) float cvec_s[192];
    __shared__ __align__(16) float bhh_s[192];
    __shared__ __align__(16) float pw_s[64];
    __shared__ __align__(16) float xrow[64];
    __shared__ __align__(16) float red[8];

    float* gates = (float*)arena;                   // [64][196] f32  P1->P2
    short* act2q = (short*)arena;                   // [64][128] swz  L2->L3
    short* act2k = (short*)(arena + 16384);
    short* act1q = (short*)(arena + 32768);         // L1->L2
    short* act1k = (short*)(arena + 49152);
    float* tf    = (float*)arena;                   // [64][68] f32   E->F1
    short* tb    = (short*)(arena + 20480);         // [64][64] swz   F1->F2

    const int tid = threadIdx.x;
    const int b = blockIdx.x;
    const int w = tid >> 6, lane = tid & 63;
    const int ln = lane & 15, lh = lane >> 4;
    const int path = w >> 2;                        // MLP: 0 = q, 1 = k
    const int wq = w & 3;

    for (int i = tid; i < 64 * 64; i += 512) { hb[i] = 0; hbN[i] = 0; hbT[i] = 0; }
    for (int i = tid; i < 64 * HS; i += 512) h32[i] = 0.f;
    for (int i = tid; i < 4096; i += 512)
        gbias_s[(i >> 6) * GBS + (i & 63)] = gate_bias[i];
    if (tid < 192) { avec_s[tid] = avec[tid]; cvec_s[tid] = cvec[tid]; bhh_s[tid] = b_hh[tid]; }
    if (tid < 64) { pw_s[tid] = pred_w[tid]; xrow[tid] = x[(size_t)b * T_STEPS * 64 + tid]; }
    const float pbv = pred_b[0];

    // ---- weight fragments (A-operand = weight rows = output cols), constant across t ----
    const short* whh_b = wsw + WHH_OFF;
    const short* l1w = path ? wsw + K1_OFF : wsw + Q1_OFF;
    const short* l2w = path ? wsw + K2_OFF : wsw + Q2_OFF;
    const short* l3w = path ? wsw + K3_OFF : wsw + Q3_OFF;
    const float* l1b = path ? k1b : q1b;
    const float* l2b = path ? k2b : q2b;
    const float* l3b = path ? k3b : q3b;

    short8 Bg[2][2], B1[2][2], B2[2][4], B3[2][4];
#pragma unroll
    for (int kk = 0; kk < 2; ++kk)
        Bg[0][kk] = *(const short8*)&whh_b[(w * 16 + ln) * 64 + kk * 32 + lh * 8];
    if (w < 4) {
#pragma unroll
        for (int kk = 0; kk < 2; ++kk)
            Bg[1][kk] = *(const short8*)&whh_b[((w + 8) * 16 + ln) * 64 + kk * 32 + lh * 8];
    }
#pragma unroll
    for (int s = 0; s < 2; ++s) {
        const int strip = wq + s * 4;
#pragma unroll
        for (int kk = 0; kk < 2; ++kk)
            B1[s][kk] = *(const short8*)&l1w[(strip * 16 + ln) * 64 + kk * 32 + lh * 8];
#pragma unroll
        for (int kk = 0; kk < 4; ++kk) {
            B2[s][kk] = *(const short8*)&l2w[(strip * 16 + ln) * 128 + kk * 32 + lh * 8];
            B3[s][kk] = *(const short8*)&l3w[(strip * 16 + ln) * 128 + kk * 32 + lh * 8];
        }
    }
    // per-lane bias vectors (4 consecutive out-cols each); global, 16B-aligned offsets
    const f32x4 b1v0 = *(const f32x4*)&l1b[wq * 16 + lh * 4];
    const f32x4 b1v1 = *(const f32x4*)&l1b[(wq + 4) * 16 + lh * 4];
    const f32x4 b2v0 = *(const f32x4*)&l2b[wq * 16 + lh * 4];
    const f32x4 b2v1 = *(const f32x4*)&l2b[(wq + 4) * 16 + lh * 4];
    const f32x4 b3v0 = *(const f32x4*)&l3b[wq * 16 + lh * 4];
    const f32x4 b3v1 = *(const f32x4*)&l3b[(wq + 4) * 16 + lh * 4];
    __syncthreads();

    for (int t = 0; t < T_STEPS; ++t) {
        // ===== P1: x prefetch, predictor(t-1), gates = h @ w_hh^T (swapped, packed) =====
        float xnext = 0.f;
        if (tid < 64 && t + 1 < T_STEPS)
            xnext = x[((size_t)b * T_STEPS + t + 1) * 64 + tid];
        if (t > 0) {
            const int c = tid >> 3, j0 = (tid & 7) * 8;
            f32x4 h0 = *(const f32x4*)&h32[c * HS + j0];
            f32x4 h1 = *(const f32x4*)&h32[c * HS + j0 + 4];
            f32x4 w0 = *(const f32x4*)&pw_s[j0];
            f32x4 w1 = *(const f32x4*)&pw_s[j0 + 4];
            float p = 0.f;
#pragma unroll
            for (int q = 0; q < 4; ++q) p = fmaf(h0[q], w0[q], fmaf(h1[q], w1[q], p));
            p += __shfl_xor(p, 1); p += __shfl_xor(p, 2); p += __shfl_xor(p, 4);
            if ((lane & 7) == 0)
                predicted[((size_t)b * (T_STEPS - 1) + (t - 1)) * 64 + c] = p + pbv;
        }
        {
            f32x4 accA[4], accB[4];
            const f32x4 bhA = *(const f32x4*)&bhh_s[w * 16 + lh * 4];
#pragma unroll
            for (int g = 0; g < 4; ++g) accA[g] = bhA;
            if (w < 4) {
                const f32x4 bhB = *(const f32x4*)&bhh_s[(w + 8) * 16 + lh * 4];
#pragma unroll
                for (int g = 0; g < 4; ++g) accB[g] = bhB;
            }
#pragma unroll
            for (int kk = 0; kk < 2; ++kk)
#pragma unroll
                for (int g = 0; g < 4; ++g) {
                    const int row = g * 16 + ln;
                    short8 hv = *(const short8*)&hb[row * 64 + ((kk * 32 + lh * 8) ^ xorr(row))];
                    accA[g] = MFMA16(Bg[0][kk], hv, accA[g]);
                    if (w < 4) accB[g] = MFMA16(Bg[1][kk], hv, accB[g]);
                }
#pragma unroll
            for (int g = 0; g < 4; ++g)
                *(f32x4*)&gates[(g * 16 + ln) * GST + w * 16 + lh * 4] = accA[g];
            if (w < 4) {
#pragma unroll
                for (int g = 0; g < 4; ++g)
                    *(f32x4*)&gates[(g * 16 + ln) * GST + (w + 8) * 16 + lh * 4] = accB[g];
            }
        }
        bar_lds();

        // ===== P2: GRU elementwise (vectorized LDS) -> h32, hbN, hbT =====
        {
            const int c = tid >> 3, j0 = (tid & 7) * 8;
            const float xv = xrow[c];
            unsigned pk[4];
#pragma unroll
            for (int h2 = 0; h2 < 2; ++h2) {
                const int jh = j0 + h2 * 4;
                f32x4 gr4 = *(const f32x4*)&gates[c * GST + jh];
                f32x4 gz4 = *(const f32x4*)&gates[c * GST + 64 + jh];
                f32x4 gn4 = *(const f32x4*)&gates[c * GST + 128 + jh];
                f32x4 ho4 = *(const f32x4*)&h32[c * HS + jh];
                f32x4 ar4 = *(const f32x4*)&avec_s[jh];
                f32x4 az4 = *(const f32x4*)&avec_s[64 + jh];
                f32x4 an4 = *(const f32x4*)&avec_s[128 + jh];
                f32x4 cr4 = *(const f32x4*)&cvec_s[jh];
                f32x4 cz4 = *(const f32x4*)&cvec_s[64 + jh];
                f32x4 cn4 = *(const f32x4*)&cvec_s[128 + jh];
                f32x4 hn4;
#pragma unroll
                for (int q = 0; q < 4; ++q) {
                    const float r = fsigm(gr4[q] + fmaf(xv, ar4[q], cr4[q]));
                    const float z = fsigm(gz4[q] + fmaf(xv, az4[q], cz4[q]));
                    const float n = ftanh(fmaf(r, gn4[q], fmaf(xv, an4[q], cn4[q])));
                    hn4[q] = fmaf(z, ho4[q] - n, n);
                }
                *(f32x4*)&h32[c * HS + jh] = hn4;
                const unsigned plo = pk2(hn4[0], hn4[1]);
                const unsigned phi = pk2(hn4[2], hn4[3]);
                pk[h2 * 2] = plo; pk[h2 * 2 + 1] = phi;
                // transposed scalar stores (bf16 halves of the packed words)
                hbT[(jh + 0) * 64 + (c ^ xorr(jh + 0))] = (short)plo;
                hbT[(jh + 1) * 64 + (c ^ xorr(jh + 1))] = (short)(plo >> 16);
                hbT[(jh + 2) * 64 + (c ^ xorr(jh + 2))] = (short)phi;
                hbT[(jh + 3) * 64 + (c ^ xorr(jh + 3))] = (short)(phi >> 16);
            }
            uint4 pv; pv.x = pk[0]; pv.y = pk[1]; pv.z = pk[2]; pv.w = pk[3];
            *(uint4*)&hbN[c * 64 + (j0 ^ xorr(c))] = pv;
        }
        bar_lds();

        // ===== L1-L3: q / k MLPs (swapped, packed stores) =====
        two_strip_sw<2, 64,  true >(hbN, B1[0], B1[1], b1v0, b1v1,
                                    path ? act1k : act1q, wq, wq + 4, ln, lh);
        bar_lds();
        two_strip_sw<4, 128, true >(path ? act1k : act1q, B2[0], B2[1], b2v0, b2v1,
                                    path ? act2k : act2q, wq, wq + 4, ln, lh);
        bar_lds();
        two_strip_sw<4, 128, false>(path ? act2k : act2q, B3[0], B3[1], b3v0, b3v1,
                                    path ? kf : qf, wq, wq + 4, ln, lh);
        bar_lds();

        // ===== E: tf = Q @ K^T via mfma(K_frag, Q_frag) -> packed f32x4 stores =====
        {
            const int qg = w & 3, kg = (w >> 2) * 2;
            f32x4 ac0 = {0,0,0,0}, ac1 = {0,0,0,0};
#pragma unroll
            for (int kk = 0; kk < 4; ++kk) {
                const int rq = qg * 16 + ln, rk0 = kg * 16 + ln, rk1 = (kg + 1) * 16 + ln;
                short8 bq = *(const short8*)&qf[rq * 128 + ((kk * 32 + lh * 8) ^ xorr(rq))];
                short8 a0 = *(const short8*)&kf[rk0 * 128 + ((kk * 32 + lh * 8) ^ xorr(rk0))];
                short8 a1 = *(const short8*)&kf[rk1 * 128 + ((kk * 32 + lh * 8) ^ xorr(rk1))];
                ac0 = MFMA16(a0, bq, ac0);
                ac1 = MFMA16(a1, bq, ac1);
            }
            const int qrow = qg * 16 + ln;
            *(f32x4*)&tf[qrow * TS + kg * 16 + lh * 4]       = ac0;
            *(f32x4*)&tf[qrow * TS + (kg + 1) * 16 + lh * 4] = ac1;
            float ss = 0.f;
#pragma unroll
            for (int q = 0; q < 4; ++q)
                ss = fmaf(ac0[q], ac0[q], fmaf(ac1[q], ac1[q], ss));
#pragma unroll
            for (int off = 1; off < 64; off <<= 1) ss += __shfl_xor(ss, off);
            if (lane == 0) red[w] = ss;
            if (tid < 64 && t + 1 < T_STEPS) xrow[tid] = xnext;
        }
        bar_lds();

        // ===== F1: normalize + gate -> fp32 matrices + (opt) mb16 + tb =====
        {
            const int ci = tid >> 3, j0 = (tid & 7) * 8;
            const float ssum = red[0]+red[1]+red[2]+red[3]+red[4]+red[5]+red[6]+red[7];
            const float inv = __builtin_amdgcn_rsqf(ssum);
            const size_t mbase = ((size_t)b * T_STEPS + t) * 4096;
            unsigned pk[4];
#pragma unroll
            for (int h2 = 0; h2 < 2; ++h2) {
                const int jh = j0 + h2 * 4;
                f32x4 t4  = *(const f32x4*)&tf[ci * TS + jh];
                f32x4 gb4 = *(const f32x4*)&gbias_s[ci * GBS + jh];
                f32x4 v4;
#pragma unroll
                for (int q = 0; q < 4; ++q) {
                    const float tv = t4[q] * inv;
                    const float g = fsigm(fabsf(tv) + gb4[q]);
                    v4[q] = tv * g;
                }
                pk[h2 * 2]     = pk2(v4[0], v4[1]);
                pk[h2 * 2 + 1] = pk2(v4[2], v4[3]);
                // fp32 output written directly
                *(f32x4*)&matrices[mbase + ci * 64 + jh] = v4;
            }
            uint4 pv; pv.x = pk[0]; pv.y = pk[1]; pv.z = pk[2]; pv.w = pk[3];
            if (use_mb16)
                *(uint4*)&mb16[mbase + ci * 64 + j0] = pv;
            *(uint4*)&tb[ci * 64 + (j0 ^ xorr(ci))] = pv;
        }
        bar_lds();

        // ===== F2: h_new = T @ h_post via mfma(hbT_frag, tb_frag) -> h32, hb (packed) =====
        {
            const int jg = w & 3, ig = (w >> 2) * 2;
            f32x4 hc0 = {0,0,0,0}, hc1 = {0,0,0,0};
#pragma unroll
            for (int kk = 0; kk < 2; ++kk) {
                const int rj = jg * 16 + ln, ri0 = ig * 16 + ln, ri1 = (ig + 1) * 16 + ln;
                short8 bt = *(const short8*)&tb [rj * 64 + ((kk * 32 + lh * 8) ^ xorr(rj))];
                short8 a0 = *(const short8*)&hbT[ri0 * 64 + ((kk * 32 + lh * 8) ^ xorr(ri0))];
                short8 a1 = *(const short8*)&hbT[ri1 * 64 + ((kk * 32 + lh * 8) ^ xorr(ri1))];
                hc0 = MFMA16(a0, bt, hc0);
                hc1 = MFMA16(a1, bt, hc1);
            }
            const int row = jg * 16 + ln;
            *(f32x4*)&h32[row * HS + ig * 16 + lh * 4]       = hc0;
            *(f32x4*)&h32[row * HS + (ig + 1) * 16 + lh * 4] = hc1;
            uint2 p0, p1;
            p0.x = pk2(hc0[0], hc0[1]); p0.y = pk2(hc0[2], hc0[3]);
            p1.x = pk2(hc1[0], hc1[1]); p1.y = pk2(hc1[2], hc1[3]);
            *(uint2*)&hb[row * 64 + ((ig * 16 + lh * 4) ^ xorr(row))]       = p0;
            *(uint2*)&hb[row * 64 + (((ig + 1) * 16 + lh * 4) ^ xorr(row))] = p1;
        }
        bar_lds();
    }
}

// ---------------- clf1 fallback: A fp32 (reg-convert) x B bf16 -> bf16 C ------------------
__global__ __launch_bounds__(256) void gemm1_kernel(
    const float* __restrict__ A, const short* __restrict__ Bw,
    const float* __restrict__ bias, short* __restrict__ Cb,
    const int M, const int N, const int K)
{
    __shared__ __align__(16) short Asb[128 * 64];
    __shared__ __align__(16) short Bsb[128 * 64];
    const int tid = threadIdx.x;
    const int w = tid >> 6, lane = tid & 63;
    const int ln = lane & 15, lh = lane >> 4;
    const int wr = w >> 1, wc = w & 1;

    const int ntc = N >> 7;
    const int g = blockIdx.x;
    const int xcd = g & 7, chunk = g >> 3;
    const int mt = xcd * ((M >> 7) >> 3) + chunk / ntc;
    const int nt = chunk % ntc;
    const int m0 = mt << 7, n0 = nt << 7;

    const int ar = tid >> 1;
    const int ac = (tid & 1) << 5;
    const short* bsrc = Bw + (size_t)(n0 + w * 32 + (lane >> 3)) * K + ((lane & 7) << 3);
    short* bdst = &Bsb[w * 32 * 64 + lane * 8];

    f32x4 acc[4][4];
#pragma unroll
    for (int m = 0; m < 4; ++m)
#pragma unroll
        for (int n = 0; n < 4; ++n) acc[m][n] = (f32x4){0, 0, 0, 0};

    for (int k0 = 0; k0 < K; k0 += 64) {
        const float* arow = A + (size_t)(m0 + ar) * K + k0 + ac;
        float4 av[8];
#pragma unroll
        for (int i = 0; i < 8; ++i) av[i] = *reinterpret_cast<const float4*>(arow + i * 4);
        short8 cv[4];
#pragma unroll
        for (int i = 0; i < 4; ++i) {
            cv[i][0] = f2bs(av[2*i].x);   cv[i][1] = f2bs(av[2*i].y);
            cv[i][2] = f2bs(av[2*i].z);   cv[i][3] = f2bs(av[2*i].w);
            cv[i][4] = f2bs(av[2*i+1].x); cv[i][5] = f2bs(av[2*i+1].y);
            cv[i][6] = f2bs(av[2*i+1].z); cv[i][7] = f2bs(av[2*i+1].w);
        }
        __syncthreads();
#pragma unroll
        for (int i = 0; i < 4; ++i)
            *reinterpret_cast<short8*>(&Asb[ar * 64 + ac + i * 8]) = cv[i];
#pragma unroll
        for (int i = 0; i < 4; ++i)
            async16(bdst + i * 512, bsrc + (size_t)i * 8 * K + k0);
        __syncthreads();
#pragma unroll
        for (int kk = 0; kk < 2; ++kk) {
            short8 af[4], bfr[4];
#pragma unroll
            for (int m = 0; m < 4; ++m)
                af[m] = *reinterpret_cast<const short8*>(&Asb[(wr*64 + m*16 + ln)*64 + kk*32 + lh*8]);
#pragma unroll
            for (int n = 0; n < 4; ++n)
                bfr[n] = *reinterpret_cast<const short8*>(&Bsb[(wc*64 + n*16 + ln)*64 + kk*32 + lh*8]);
#pragma unroll
            for (int m = 0; m < 4; ++m)
#pragma unroll
                for (int n = 0; n < 4; ++n)
                    acc[m][n] = MFMA16(af[m], bfr[n], acc[m][n]);
        }
    }
#pragma unroll
    for (int n = 0; n < 4; ++n) {
        const int col = n0 + wc * 64 + n * 16 + ln;
        const float bv = bias[col];
#pragma unroll
        for (int m = 0; m < 4; ++m)
#pragma unroll
            for (int q = 0; q < 4; ++q) {
                const int row = m0 + wr * 64 + m * 16 + lh * 4 + q;
                Cb[(size_t)row * N + col] = f2bs(fmaxf(acc[m][n][q] + bv, 0.f));
            }
    }
}

// ---------------- bf16 x bf16 GEMM via gload_lds (clf1 / clf2) ----------------------------
__global__ __launch_bounds__(256) void gemm2_kernel(
    const short* __restrict__ Ab, const short* __restrict__ Bw,
    const float* __restrict__ bias, short* __restrict__ Cb,
    const int M, const int N, const int K)
{
    __shared__ __align__(16) short Asb[128 * 64];
    __shared__ __align__(16) short Bsb[128 * 64];
    const int tid = threadIdx.x;
    const int w = tid >> 6, lane = tid & 63;
    const int ln = lane & 15, lh = lane >> 4;
    const int wr = w >> 1, wc = w & 1;

    const int ntc = N >> 7;
    const int g = blockIdx.x;
    const int xcd = g & 7, chunk = g >> 3;
    const int mt = xcd * ((M >> 7) >> 3) + chunk / ntc;
    const int nt = chunk % ntc;
    const int m0 = mt << 7, n0 = nt << 7;

    const short* asrc = Ab + (size_t)(m0 + w * 32 + (lane >> 3)) * K + ((lane & 7) << 3);
    const short* bsrc = Bw + (size_t)(n0 + w * 32 + (lane >> 3)) * K + ((lane & 7) << 3);
    short* adst = &Asb[w * 32 * 64 + lane * 8];
    short* bdst = &Bsb[w * 32 * 64 + lane * 8];

    f32x4 acc[4][4];
#pragma unroll
    for (int m = 0; m < 4; ++m)
#pragma unroll
        for (int n = 0; n < 4; ++n) acc[m][n] = (f32x4){0, 0, 0, 0};

    for (int k0 = 0; k0 < K; k0 += 64) {
        __syncthreads();
#pragma unroll
        for (int i = 0; i < 4; ++i) {
            async16(adst + i * 512, asrc + (size_t)i * 8 * K + k0);
            async16(bdst + i * 512, bsrc + (size_t)i * 8 * K + k0);
        }
        __syncthreads();
#pragma unroll
        for (int kk = 0; kk < 2; ++kk) {
            short8 af[4], bfr[4];
#pragma unroll
            for (int m = 0; m < 4; ++m)
                af[m] = *reinterpret_cast<const short8*>(&Asb[(wr*64 + m*16 + ln)*64 + kk*32 + lh*8]);
#pragma unroll
            for (int n = 0; n < 4; ++n)
                bfr[n] = *reinterpret_cast<const short8*>(&Bsb[(wc*64 + n*16 + ln)*64 + kk*32 + lh*8]);
#pragma unroll
            for (int m = 0; m < 4; ++m)
#pragma unroll
                for (int n = 0; n < 4; ++n)
                    acc[m][n] = MFMA16(af[m], bfr[n], acc[m][n]);
        }
    }
#pragma unroll
    for (int n = 0; n < 4; ++n) {
        const int col = n0 + wc * 64 + n * 16 + ln;
        const float bv = bias[col];
#pragma unroll
        for (int m = 0; m < 4; ++m)
#pragma unroll
            for (int q = 0; q < 4; ++q) {
                const int row = m0 + wr * 64 + m * 16 + lh * 4 + q;
                Cb[(size_t)row * N + col] = f2bs(fmaxf(acc[m][n][q] + bv, 0.f));
            }
    }
}

// ---------------- clf3: [M,1024] bf16 -> time_logits [M,2] --------------------------------
__global__ __launch_bounds__(256) void clf3_kernel(const short* __restrict__ h2b,
    const float* __restrict__ w3, const float* __restrict__ b3, float* __restrict__ TL)
{
    const int lane = threadIdx.x & 63;
    const int w = threadIdx.x >> 6;
    const size_t r = (size_t)blockIdx.x * 4 + w;
    const short* hr = h2b + r * 1024;
    float a0 = 0.f, a1 = 0.f;
#pragma unroll
    for (int half = 0; half < 2; ++half) {
        const int k = half * 512 + lane * 8;
        short8 hv = *(const short8*)&hr[k];
#pragma unroll
        for (int u = 0; u < 8; ++u) {
            const float hf = bf2f(hv[u]);
            a0 = fmaf(hf, w3[k + u], a0);
            a1 = fmaf(hf, w3[1024 + k + u], a1);
        }
    }
    for (int off = 32; off; off >>= 1) { a0 += __shfl_xor(a0, off); a1 += __shfl_xor(a1, off); }
    if (lane == 0) {
        TL[r * 2 + 0] = a0 + b3[0];
        TL[r * 2 + 1] = a1 + b3[1];
    }
}

__global__ void logits_kernel(const float* __restrict__ TL, float* __restrict__ out)
{
    const int tid = threadIdx.x;
    if (tid >= 128) return;
    const int b = tid >> 1, o = tid & 1;
    float s = 0.f;
    for (int t = 0; t < T_STEPS; ++t) s += TL[((size_t)b * T_STEPS + t) * 2 + o];
    out[b * 2 + o] = s * (1.0f / 256.0f);
}

extern "C" void kernel_launch(void* const* d_in, const int* in_sizes, int n_in,
                              void* d_out, int out_size, void* d_ws, size_t ws_size,
                              hipStream_t stream)
{
    const float* x       = (const float*)d_in[0];
    const float* embed_w = (const float*)d_in[1];
    const float* embed_b = (const float*)d_in[2];
    const float* w_ih    = (const float*)d_in[3];
    const float* w_hh    = (const float*)d_in[4];
    const float* b_ih    = (const float*)d_in[5];
    const float* b_hh    = (const float*)d_in[6];
    const float* q1w = (const float*)d_in[7],  *q1b = (const float*)d_in[8];
    const float* q2w = (const float*)d_in[9],  *q2b = (const float*)d_in[10];
    const float* q3w = (const float*)d_in[11], *q3b = (const float*)d_in[12];
    const float* k1w = (const float*)d_in[13], *k1b = (const float*)d_in[14];
    const float* k2w = (const float*)d_in[15], *k2b = (const float*)d_in[16];
    const float* k3w = (const float*)d_in[17], *k3b = (const float*)d_in[18];
    const float* gate_bias = (const float*)d_in[19];
    const float* c1w = (const float*)d_in[20], *c1b = (const float*)d_in[21];
    const float* c2w = (const float*)d_in[22], *c2b = (const float*)d_in[23];
    const float* c3w = (const float*)d_in[24], *c3b = (const float*)d_in[25];
    const float* pw  = (const float*)d_in[26], *pb  = (const float*)d_in[27];

    float* out       = (float*)d_out;
    float* logits    = out;
    float* matrices  = out + MAT_OFF;
    float* TL        = out + TL_OFF;
    float* predicted = out + PRED_OFF;
    float* xcopy     = out + XC_OFF;

    float* ws   = (float*)d_ws;
    float* avec = ws;
    float* cvec = ws + 192;
    short* wsw  = (short*)((char*)d_ws + WSW_BYTE_OFF);
    short* c1wb = (short*)((char*)d_ws + C1WB_BYTE);
    short* c2wb = (short*)((char*)d_ws + C2WB_BYTE);
    short* h1b  = (short*)((char*)d_ws + H1B_BYTE);
    short* h2b  = (short*)((char*)d_ws + H2B_BYTE);

    const int use_mb16 = (ws_size >= MB16_BYTE + 134217728ULL) ? 1 : 0;
    short* mb16 = use_mb16 ? (short*)((char*)d_ws + MB16_BYTE) : (short*)d_ws;

    precompute_kernel<<<1, 256, 0, stream>>>(w_ih, embed_w, embed_b, b_ih, avec, cvec);

    // merged fp32->bf16 conversions + xcopy in one launch (10 segments, 11352 blocks)
    tobf16_all_kernel<<<11352, 256, 0, stream>>>(
        w_hh, q1w, k1w, q2w, k2w, q3w, k3w, c1w, c2w, wsw, c1wb, c2wb, x, xcopy);

    scan_kernel<<<B_BATCH, 512, 0, stream>>>(x, b_hh, avec, cvec, wsw,
        q1b, q2b, q3b, k1b, k2b, k3b, gate_bias, pw, pb, matrices, predicted,
        mb16, use_mb16);

    const int Mtot = B_BATCH * T_STEPS;   // 16384
    if (use_mb16) {
        gemm2_kernel<<<(Mtot / 128) * (2048 / 128), 256, 0, stream>>>(
            mb16, c1wb, c1b, h1b, Mtot, 2048, 4096);
    } else {
        gemm1_kernel<<<(Mtot / 128) * (2048 / 128), 256, 0, stream>>>(
            matrices, c1wb, c1b, h1b, Mtot, 2048, 4096);
    }
    gemm2_kernel<<<(Mtot / 128) * (1024 / 128), 256, 0, stream>>>(
        h1b, c2wb, c2b, h2b, Mtot, 1024, 2048);
    clf3_kernel<<<Mtot / 4, 256, 0, stream>>>(h2b, c3w, c3b, TL);
    logits_kernel<<<1, 128, 0, stream>>>(TL, logits);
}